// Round 14
// baseline (330.676 us; speedup 1.0000x reference)
//
#include <hip/hip_runtime.h>
#include <hip/hip_bf16.h>

typedef unsigned short u16;
typedef __attribute__((ext_vector_type(8))) short bf16x8;
typedef __attribute__((ext_vector_type(4))) float f32x4;
typedef __attribute__((ext_vector_type(8))) u16 u16x8;
typedef __attribute__((ext_vector_type(4))) u16 u16x4;

#define T_SEQ 2048
#define HID 4096
#define NQ 32
#define NKV 8
#define DH 128
#define WIN 1024

__device__ __forceinline__ u16 f2bf(float f) {
  union { float f; unsigned int u; } v; v.f = f;
  unsigned int u = v.u;
  unsigned int r = (u + 0x7FFFu + ((u >> 16) & 1u)) >> 16;
  return (u16)r;
}
__device__ __forceinline__ float bf2f(u16 b) {
  union { unsigned int u; float f; } v; v.u = ((unsigned int)b) << 16;
  return v.f;
}

__device__ __forceinline__ void gload16(const void* g, void* l) {
  __builtin_amdgcn_global_load_lds(
      (const __attribute__((address_space(1))) unsigned int*)g,
      (__attribute__((address_space(3))) unsigned int*)l, 16, 0, 0);
}

// ---------------- elementwise f32 -> bf16 ----------------
__global__ __launch_bounds__(256) void f32_to_bf16(const float* __restrict__ in,
                                                   u16* __restrict__ out, int n) {
  int i = (blockIdx.x * 256 + threadIdx.x) * 8;
  if (i >= n) return;
  float4 a = *(const float4*)(in + i);
  float4 b = *(const float4*)(in + i + 4);
  u16x8 r;
  r[0] = f2bf(a.x); r[1] = f2bf(a.y); r[2] = f2bf(a.z); r[3] = f2bf(a.w);
  r[4] = f2bf(b.x); r[5] = f2bf(b.y); r[6] = f2bf(b.z); r[7] = f2bf(b.w);
  *(u16x8*)(out + i) = r;
}

// ---------------- tiled transpose f32 (R x C) -> bf16 (C x R), 64x64 float4 ----------------
__global__ __launch_bounds__(256) void transpose_f32_to_bf16(const float* __restrict__ in,
                                                             u16* __restrict__ out,
                                                             int R, int C) {
  __shared__ float tile[64][65];
  int c0 = blockIdx.x * 64, r0 = blockIdx.y * 64;
  int tx = threadIdx.x, ty = threadIdx.y;    // 16 x 16
#pragma unroll
  for (int i = 0; i < 64; i += 16) {
    float4 v = *(const float4*)(in + (size_t)(r0 + ty + i) * C + c0 + tx * 4);
    tile[ty + i][tx * 4 + 0] = v.x;
    tile[ty + i][tx * 4 + 1] = v.y;
    tile[ty + i][tx * 4 + 2] = v.z;
    tile[ty + i][tx * 4 + 3] = v.w;
  }
  __syncthreads();
#pragma unroll
  for (int i = 0; i < 64; i += 16) {
    u16x4 o;
#pragma unroll
    for (int j = 0; j < 4; ++j) o[j] = f2bf(tile[tx * 4 + j][ty + i]);
    *(u16x4*)(out + (size_t)(c0 + ty + i) * R + r0 + tx * 4) = o;
  }
}

// ---------------- 256xBN 2-window full-fill GEMM (R12, used for gemm1) ----------------
// W1: rd afA(mh0) + ALL B frags | stage A(t+1) u0..3 [slot^1] | barrier |
//     lgkm0 | MFMA mh0 x all nf | barrier
// W2: rd afB(mh1) | stage B(t+2) u0..NB-1 [slot] | barrier | lgkm0 |
//     MFMA mh1 x all nf | vmcnt(NB) | barrier
template <int NF, bool BF16OUT>
__global__ __launch_bounds__(512, 2) void gemm_2w(const u16* __restrict__ A,
                                                  const u16* __restrict__ Bt,
                                                  void* __restrict__ Cv,
                                                  int N, int K, int NT) {
  constexpr int HN = NF * 16;
  constexpr int BN = 4 * HN;
  constexpr int NB = BN / 64;
  __shared__ u16 lsA[2][16384];
  __shared__ u16 lsB[2][BN * 64];
  const int tid = threadIdx.x;
  const int lane = tid & 63, w = tid >> 6;
  const int wm = w >> 1, wn = w & 1;
  const int l15 = lane & 15, l4 = lane >> 4;

  const int nwg = gridDim.x;
  const int cpx = nwg >> 3;
  const int bid = blockIdx.x;
  const int swz = (bid & 7) * cpx + (bid >> 3);
  const int bm = (swz & 7) * 256;
  const int bn = (swz >> 3) * BN;

  auto stageA = [&](int unit, int slot, int kt) {
    int r = tid >> 3, cp = tid & 7;
    int scp = cp ^ (r & 7);
    gload16(A + (size_t)(bm + unit * 64 + r) * K + kt * 64 + scp * 8,
            (char*)lsA[slot] + (unit * 512 + tid) * 16);
  };
  auto stageB = [&](int unit, int slot, int kt) {
    int r = tid >> 3, cp = tid & 7;
    int scp = cp ^ (r & 7);
    gload16(Bt + (size_t)(bn + unit * 64 + r) * K + kt * 64 + scp * 8,
            (char*)lsB[slot] + (unit * 512 + tid) * 16);
  };
  auto rdA = [&](int slot, int mh, int mf, int ks) -> bf16x8 {
    int r = wm * 64 + mh * 32 + mf * 16 + l15;
    int ch = (ks * 4 + l4) ^ (r & 7);
    return *(const bf16x8*)(lsA[slot] + r * 64 + ch * 8);
  };
  auto rdB = [&](int slot, int nh, int nf, int ks) -> bf16x8 {
    int r = wn * 2 * HN + nh * HN + nf * 16 + l15;
    int ch = (ks * 4 + l4) ^ (r & 7);
    return *(const bf16x8*)(lsB[slot] + r * 64 + ch * 8);
  };

#define WAIT_NB() do { if constexpr (NB == 3) asm volatile("s_waitcnt vmcnt(3)" ::: "memory"); \
                       else                   asm volatile("s_waitcnt vmcnt(2)" ::: "memory"); } while (0)

  f32x4 acc[4][2 * NF] = {};
  bf16x8 afA[2][2], afB[2][2], bfr[2 * NF][2];

  stageA(0, 0, 0); stageA(1, 0, 0); stageA(2, 0, 0); stageA(3, 0, 0);
#pragma unroll
  for (int u = 0; u < NB; ++u) stageB(u, 0, 0);
#pragma unroll
  for (int u = 0; u < NB; ++u) stageB(u, 1, 1);
  WAIT_NB();
  __builtin_amdgcn_s_barrier();

  for (int t = 0; t < NT; ++t) {
    const int s = t & 1;
    const int ktA = (t + 1 < NT) ? t + 1 : NT - 1;
    const int ktB = (t + 2 < NT) ? t + 2 : NT - 1;

    // ---- W1 ----
#pragma unroll
    for (int mf = 0; mf < 2; ++mf)
#pragma unroll
      for (int ks = 0; ks < 2; ++ks) afA[mf][ks] = rdA(s, 0, mf, ks);
#pragma unroll
    for (int nf = 0; nf < NF; ++nf)
#pragma unroll
      for (int ks = 0; ks < 2; ++ks) {
        bfr[nf][ks] = rdB(s, 0, nf, ks);
        bfr[NF + nf][ks] = rdB(s, 1, nf, ks);
      }
    stageA(0, s ^ 1, ktA); stageA(1, s ^ 1, ktA);
    stageA(2, s ^ 1, ktA); stageA(3, s ^ 1, ktA);
    __builtin_amdgcn_s_barrier();
    asm volatile("s_waitcnt lgkmcnt(0)" ::: "memory");
    __builtin_amdgcn_sched_barrier(0);
    __builtin_amdgcn_s_setprio(1);
#pragma unroll
    for (int mf = 0; mf < 2; ++mf)
#pragma unroll
      for (int nf = 0; nf < 2 * NF; ++nf) {
        acc[mf][nf] = __builtin_amdgcn_mfma_f32_16x16x32_bf16(afA[mf][0], bfr[nf][0], acc[mf][nf], 0, 0, 0);
        acc[mf][nf] = __builtin_amdgcn_mfma_f32_16x16x32_bf16(afA[mf][1], bfr[nf][1], acc[mf][nf], 0, 0, 0);
      }
    __builtin_amdgcn_s_setprio(0);
    __builtin_amdgcn_s_barrier();

    // ---- W2 ----
#pragma unroll
    for (int mf = 0; mf < 2; ++mf)
#pragma unroll
      for (int ks = 0; ks < 2; ++ks) afB[mf][ks] = rdA(s, 1, mf, ks);
#pragma unroll
    for (int u = 0; u < NB; ++u) stageB(u, s, ktB);
    __builtin_amdgcn_s_barrier();
    asm volatile("s_waitcnt lgkmcnt(0)" ::: "memory");
    __builtin_amdgcn_sched_barrier(0);
    __builtin_amdgcn_s_setprio(1);
#pragma unroll
    for (int mf = 0; mf < 2; ++mf)
#pragma unroll
      for (int nf = 0; nf < 2 * NF; ++nf) {
        acc[2 + mf][nf] = __builtin_amdgcn_mfma_f32_16x16x32_bf16(afB[mf][0], bfr[nf][0], acc[2 + mf][nf], 0, 0, 0);
        acc[2 + mf][nf] = __builtin_amdgcn_mfma_f32_16x16x32_bf16(afB[mf][1], bfr[nf][1], acc[2 + mf][nf], 0, 0, 0);
      }
    __builtin_amdgcn_s_setprio(0);
    WAIT_NB();
    __builtin_amdgcn_s_barrier();
  }

  asm volatile("s_waitcnt vmcnt(0)" ::: "memory");

#pragma unroll
  for (int mi = 0; mi < 4; ++mi)
#pragma unroll
    for (int ni = 0; ni < 2 * NF; ++ni) {
      int row = bm + wm * 64 + mi * 16 + l4 * 4;
      int col = bn + wn * 2 * HN + ni * 16 + l15;
      if constexpr (BF16OUT) {
        u16* dst = (u16*)Cv;
#pragma unroll
        for (int j = 0; j < 4; ++j)
          dst[(size_t)(row + j) * N + col] = f2bf(acc[mi][ni][j]);
      } else {
        float* p = (float*)Cv + (size_t)row * N + col;
        p[0] = acc[mi][ni][0];
        p[(size_t)N] = acc[mi][ni][1];
        p[2 * (size_t)N] = acc[mi][ni][2];
        p[3 * (size_t)N] = acc[mi][ni][3];
      }
    }
#undef WAIT_NB
}

// ---------------- gemm2_p: 256x128 one-ahead pipelined GEMM (f32 out) ----------------
// C(2048x4096) = A(bf16 2048x4096) * Bt(bf16 4096x4096)^T.  BM=256, BN=128,
// BK=64.  8 waves 4Mx2N (per-wave 64x64 = 4mf x 4nf).  LDS 128KB: A 3-slot
// ring (3x32KB), B 2-slot (2x16KB).  MFMA runs one window LATE: each window's
// ds_reads prefetch the NEXT window's fragments into a separate register bank,
// so the lgkmcnt(0) lands after an MFMA cluster that doesn't consume them --
// LDS drain overlaps the matrix pipe (the 42%-util serial ceiling breaker).
//   W1(t): stage A(t+2)->slot(t+2)%3; vmcnt(4) [retires A(t+1)+B(t+1)];
//          rd afB(t)[slot t%3] + bfr_next(t+1)[B slot (t+1)&1];
//          MFMA mh0 (afA_cur x bfr_cur); lgkm0; sched_barrier; barrier.
//   W2(t): rd afA_next(t+1)[slot (t+1)%3]; stage B(t+2)->slot t&1;
//          MFMA mh1 (afB x bfr_cur); lgkm0; sched_barrier; barrier.
// vmcnt ledger: outstanding at W1(t) vmcnt = A(t+1)4 + B(t+1)2 + A(t+2)4 = 10,
// vmcnt(4) retires oldest 6 = A(t+1)+B(t+1).  Leads: A(t+1) 3 windows,
// B(t+1) 2 windows.  Slot overwrite hazards: A slot reused after 2 barriers
// past its last reader; B slot t&1 (B(t)) last read in W1(t-1), staged W2(t)
// >=2 barriers later.  Tail: kt clamps to NT-1 (dummy re-stage/re-read of
// resident data; vmcnt arithmetic exact).  Banks ping-pong via 2x unroll.
#define MFMA16(a, b, c) __builtin_amdgcn_mfma_f32_16x16x32_bf16(a, b, c, 0, 0, 0)
__global__ __launch_bounds__(512, 2) void gemm2_p(const u16* __restrict__ A,
                                                  const u16* __restrict__ Bt,
                                                  float* __restrict__ C,
                                                  int N, int K, int NT) {
  __shared__ u16 lsA[3][16384];   // 3 x [256 rows][64 k] = 96KB
  __shared__ u16 lsB[2][8192];    // 2 x [128 rows][64 k] = 32KB
  const int tid = threadIdx.x;
  const int lane = tid & 63, w = tid >> 6;
  const int wm = w >> 1, wn = w & 1;           // 4M x 2N
  const int l15 = lane & 15, l4 = lane >> 4;

  const int nwg = gridDim.x;
  const int cpx = nwg >> 3;
  const int bid = blockIdx.x;
  const int swz = (bid & 7) * cpx + (bid >> 3);
  const int bm = (swz & 7) * 256;
  const int bn = (swz >> 3) * 128;

  auto stageA = [&](int unit, int slot, int kt) {
    int r = tid >> 3, cp = tid & 7;
    int scp = cp ^ (r & 7);
    gload16(A + (size_t)(bm + unit * 64 + r) * K + kt * 64 + scp * 8,
            (char*)lsA[slot] + (unit * 512 + tid) * 16);
  };
  auto stageB = [&](int unit, int slot, int kt) {
    int r = tid >> 3, cp = tid & 7;
    int scp = cp ^ (r & 7);
    gload16(Bt + (size_t)(bn + unit * 64 + r) * K + kt * 64 + scp * 8,
            (char*)lsB[slot] + (unit * 512 + tid) * 16);
  };
  auto rdA = [&](int slot, int mfi, int ks) -> bf16x8 {
    int r = wm * 64 + mfi * 16 + l15;
    int ch = (ks * 4 + l4) ^ (r & 7);
    return *(const bf16x8*)(lsA[slot] + r * 64 + ch * 8);
  };
  auto rdB = [&](int slot, int nf, int ks) -> bf16x8 {
    int r = wn * 64 + nf * 16 + l15;
    int ch = (ks * 4 + l4) ^ (r & 7);
    return *(const bf16x8*)(lsB[slot] + r * 64 + ch * 8);
  };

  f32x4 acc[4][4] = {};
  bf16x8 afA0[4], afA1[4], bfr0_[8], bfr1_[8], afB[4];

  // prologue: A(0)->s0, B(0)->s0b, A(1)->s1, B(1)->s1b (12 issues);
  // vmcnt(6) -> A(0)+B(0) resident; read tile0's W1 frags into bank0.
  stageA(0, 0, 0); stageA(1, 0, 0); stageA(2, 0, 0); stageA(3, 0, 0);
  stageB(0, 0, 0); stageB(1, 0, 0);
  stageA(0, 1, 1); stageA(1, 1, 1); stageA(2, 1, 1); stageA(3, 1, 1);
  stageB(0, 1, 1); stageB(1, 1, 1);
  asm volatile("s_waitcnt vmcnt(6)" ::: "memory");
  __builtin_amdgcn_s_barrier();
#pragma unroll
  for (int mf = 0; mf < 2; ++mf)
#pragma unroll
    for (int ks = 0; ks < 2; ++ks) afA0[mf * 2 + ks] = rdA(0, mf, ks);
#pragma unroll
  for (int nf = 0; nf < 4; ++nf)
#pragma unroll
    for (int ks = 0; ks < 2; ++ks) bfr0_[nf * 2 + ks] = rdB(0, nf, ks);
  asm volatile("s_waitcnt lgkmcnt(0)" ::: "memory");
  __builtin_amdgcn_sched_barrier(0);

#define TILE_P(T, AFC, BFC, AFN, BFN) {                                        \
    const int s3 = (T) % 3, s3n = ((T) + 1) % 3, s3s = ((T) + 2) % 3;          \
    const int s2 = (T) & 1, s2n = ((T) + 1) & 1;                               \
    const int ktt = ((T) + 2 < NT) ? (T) + 2 : NT - 1;                         \
    /* ---- W1 ---- */                                                         \
    stageA(0, s3s, ktt); stageA(1, s3s, ktt);                                  \
    stageA(2, s3s, ktt); stageA(3, s3s, ktt);                                  \
    asm volatile("s_waitcnt vmcnt(4)" ::: "memory");                           \
    _Pragma("unroll")                                                          \
    for (int mf = 0; mf < 2; ++mf)                                             \
      _Pragma("unroll")                                                        \
      for (int ks = 0; ks < 2; ++ks) afB[mf * 2 + ks] = rdA(s3, 2 + mf, ks);   \
    _Pragma("unroll")                                                          \
    for (int nf = 0; nf < 4; ++nf)                                             \
      _Pragma("unroll")                                                        \
      for (int ks = 0; ks < 2; ++ks) BFN[nf * 2 + ks] = rdB(s2n, nf, ks);      \
    __builtin_amdgcn_s_setprio(1);                                             \
    _Pragma("unroll")                                                          \
    for (int mf = 0; mf < 2; ++mf)                                             \
      _Pragma("unroll")                                                        \
      for (int nf = 0; nf < 4; ++nf) {                                         \
        acc[mf][nf] = MFMA16(AFC[mf * 2 + 0], BFC[nf * 2 + 0], acc[mf][nf]);   \
        acc[mf][nf] = MFMA16(AFC[mf * 2 + 1], BFC[nf * 2 + 1], acc[mf][nf]);   \
      }                                                                        \
    __builtin_amdgcn_s_setprio(0);                                             \
    asm volatile("s_waitcnt lgkmcnt(0)" ::: "memory");                         \
    __builtin_amdgcn_sched_barrier(0);                                         \
    __builtin_amdgcn_s_barrier();                                              \
    /* ---- W2 ---- */                                                         \
    _Pragma("unroll")                                                          \
    for (int mf = 0; mf < 2; ++mf)                                             \
      _Pragma("unroll")                                                        \
      for (int ks = 0; ks < 2; ++ks) AFN[mf * 2 + ks] = rdA(s3n, mf, ks);      \
    stageB(0, s2, ktt); stageB(1, s2, ktt);                                    \
    __builtin_amdgcn_s_setprio(1);                                             \
    _Pragma("unroll")                                                          \
    for (int mf = 0; mf < 2; ++mf)                                             \
      _Pragma("unroll")                                                        \
      for (int nf = 0; nf < 4; ++nf) {                                         \
        acc[2 + mf][nf] = MFMA16(afB[mf * 2 + 0], BFC[nf * 2 + 0], acc[2 + mf][nf]); \
        acc[2 + mf][nf] = MFMA16(afB[mf * 2 + 1], BFC[nf * 2 + 1], acc[2 + mf][nf]); \
      }                                                                        \
    __builtin_amdgcn_s_setprio(0);                                             \
    asm volatile("s_waitcnt lgkmcnt(0)" ::: "memory");                         \
    __builtin_amdgcn_sched_barrier(0);                                         \
    __builtin_amdgcn_s_barrier();                                              \
  }

  for (int t = 0; t < NT; t += 2) {
    TILE_P(t, afA0, bfr0_, afA1, bfr1_);
    TILE_P(t + 1, afA1, bfr1_, afA0, bfr0_);
  }
#undef TILE_P

  asm volatile("s_waitcnt vmcnt(0)" ::: "memory");

#pragma unroll
  for (int mi = 0; mi < 4; ++mi)
#pragma unroll
    for (int ni = 0; ni < 4; ++ni) {
      int row = bm + wm * 64 + mi * 16 + l4 * 4;
      int col = bn + wn * 64 + ni * 16 + l15;
      float* p = C + (size_t)row * N + col;
      p[0] = acc[mi][ni][0];
      p[(size_t)N] = acc[mi][ni][1];
      p[2 * (size_t)N] = acc[mi][ni][2];
      p[3 * (size_t)N] = acc[mi][ni][3];
    }
}

// ---------------- RMSNorm + RoPE + layout (bf16 qkv in; Q scaled; V transposed) -------
__global__ __launch_bounds__(256) void rope_kernel(const u16* __restrict__ qkv,
                                                   const float* __restrict__ cosb,
                                                   const float* __restrict__ sinb,
                                                   const float* __restrict__ qw,
                                                   const float* __restrict__ kw,
                                                   u16* __restrict__ Qo,
                                                   u16* __restrict__ Ko,
                                                   u16* __restrict__ Vt) {
  int wid = threadIdx.x >> 6, lane = threadIdx.x & 63;
  int item = blockIdx.x * 4 + wid;          // item = t*48 + hid
  int t = item / 48, hid = item % 48;
  const u16* x = qkv + (size_t)t * 6144 + hid * 128;
  float x1 = bf2f(x[lane]), x2 = bf2f(x[lane + 64]);
  if (hid < NQ + NKV) {
    float ss = x1 * x1 + x2 * x2;
    for (int off = 32; off; off >>= 1) ss += __shfl_xor(ss, off);
    float inv = rsqrtf(ss * (1.0f / 128.0f) + 1e-6f);
    const float* wn = (hid < NQ) ? qw : kw;
    float n1 = x1 * inv * wn[lane], n2 = x2 * inv * wn[lane + 64];
    float c1 = cosb[t * 128 + lane], s1 = sinb[t * 128 + lane];
    float c2 = cosb[t * 128 + lane + 64], s2 = sinb[t * 128 + lane + 64];
    float o1 = n1 * c1 - n2 * s1;
    float o2 = n2 * c2 + n1 * s2;
    if (hid < NQ) {
      const float scale = 0.08838834764831845f;  // fold 1/sqrt(128) into Q
      u16* q = Qo + ((size_t)hid * T_SEQ + t) * 128;
      q[lane] = f2bf(o1 * scale); q[lane + 64] = f2bf(o2 * scale);
    } else {
      int h = hid - NQ;
      u16* k = Ko + ((size_t)h * T_SEQ + t) * 128;
      k[lane] = f2bf(o1); k[lane + 64] = f2bf(o2);
    }
  } else {
    int h = hid - (NQ + NKV);
    Vt[((size_t)h * 128 + lane) * T_SEQ + t] = x[lane];
    Vt[((size_t)h * 128 + lane + 64) * T_SEQ + t] = x[lane + 64];
  }
}

// ---------------- flash attention: 4 waves/block, QBLK=64, KVBLK=64 (R11 form) ----------------
__global__ __launch_bounds__(256) void attn_kernel(const u16* __restrict__ Q,
                                                   const u16* __restrict__ Kb,
                                                   const u16* __restrict__ Vt,
                                                   u16* __restrict__ O) {
  __shared__ u16 kls[2][64 * 128];   // 16KB per buf
  __shared__ u16 vls[2][128 * 64];   // 16KB per buf
  __shared__ u16 plds[4][16 * 72];   // per-wave P [16 q][64 k] pad to 72

  const int tid = threadIdx.x;
  const int lane = tid & 63, w = tid >> 6;
  const int l15 = lane & 15, l4 = lane >> 4;
  const int h = blockIdx.x;          // q head
  const int q0 = blockIdx.y * 64;    // block q base
  const int wq0 = q0 + w * 16;       // wave q base
  const int kvh = h >> 2;

  bf16x8 qf[4];
  {
    const u16* qrow = Q + ((size_t)h * T_SEQ + (wq0 + l15)) * DH;
    for (int ks = 0; ks < 4; ++ks)
      qf[ks] = *(const bf16x8*)(qrow + ks * 32 + l4 * 8);
  }

  f32x4 acc[8] = {};
  float m = -1e30f, lsum = 0.f;

  int ks0 = q0 - (WIN - 1); if (ks0 < 0) ks0 = 0;
  ks0 &= ~63;
  const int kend = q0;               // tile [q0, q0+63] covers the diagonal

  auto stage = [&](int b, int k0) {
#pragma unroll
    for (int c = 0; c < 4; ++c) {
      int base = w * 4096 + c * 1024;            // bytes in 16KB tile
      int idx = base / 16 + lane;                // 16B chunk index 0..1023
      {
        int row = idx >> 4;                      // K row (64 rows x 256B)
        int col = (idx & 15) ^ (row & 7);
        gload16(Kb + ((size_t)kvh * T_SEQ + k0 + row) * DH + col * 8,
                (char*)kls[b] + base);
      }
      {
        int d = idx >> 3;                        // V^T row (128 rows x 128B)
        int ch = (idx & 7) ^ (d & 7);
        gload16(Vt + ((size_t)kvh * DH + d) * T_SEQ + k0 + ch * 8,
                (char*)vls[b] + base);
      }
    }
  };

  stage(0, ks0);
  int buf = 0;
  for (int k0 = ks0; k0 <= kend; k0 += 64) {
    bool more = (k0 + 64 <= kend);
    if (more) stage(buf ^ 1, k0 + 64);
    if (more) { asm volatile("s_waitcnt vmcnt(8)" ::: "memory"); }
    else      { asm volatile("s_waitcnt vmcnt(0)" ::: "memory"); }
    __builtin_amdgcn_s_barrier();
    __builtin_amdgcn_sched_barrier(0);

    // wave skip: does [k0, k0+63] intersect [wq0-1023, wq0+15]?
    if (k0 <= wq0 + 15 && k0 + 63 >= wq0 - (WIN - 1)) {
      // ---- QK^T (swapped): S^T[k][q], A=K from LDS, B=Q regs ----
      f32x4 st[4];
      __builtin_amdgcn_s_setprio(1);
#pragma unroll
      for (int kh = 0; kh < 4; ++kh) {
        f32x4 s = {};
        int row = kh * 16 + l15;
        const char* kb = (const char*)kls[buf] + row * 256;
#pragma unroll
        for (int ks = 0; ks < 4; ++ks) {
          int chunk = (ks * 4 + l4) ^ (row & 7);
          bf16x8 kf = *(const bf16x8*)(kb + chunk * 16);
          s = __builtin_amdgcn_mfma_f32_16x16x32_bf16(kf, qf[ks], s, 0, 0, 0);
        }
        st[kh] = s;
      }
      __builtin_amdgcn_s_setprio(0);
      // ---- mask + online softmax (lane owns q = wq0+l15) ----
      const int q = wq0 + l15;
      float pv[4][4];
      float mx = -3e38f;
      // interior: all k in tile allowed for ALL q rows of this wave
      if (k0 + 64 <= wq0 && k0 >= wq0 - 1008) {
#pragma unroll
        for (int kh = 0; kh < 4; ++kh)
#pragma unroll
          for (int i = 0; i < 4; ++i) {
            pv[kh][i] = st[kh][i];
            mx = fmaxf(mx, pv[kh][i]);
          }
      } else {
#pragma unroll
        for (int kh = 0; kh < 4; ++kh)
#pragma unroll
          for (int i = 0; i < 4; ++i) {
            int k = k0 + kh * 16 + l4 * 4 + i;
            bool ok = ((k >> 2) <= (q >> 2)) && (q - k < WIN);
            float s = ok ? st[kh][i] : -3e38f;
            pv[kh][i] = s;
            mx = fmaxf(mx, s);
          }
      }
      mx = fmaxf(mx, __shfl_xor(mx, 16));
      mx = fmaxf(mx, __shfl_xor(mx, 32));
      if (!__all(mx <= m + 8.f)) {      // defer-max
        float mn = fmaxf(m, mx);
        float sc = __expf(m - mn);
        m = mn;
        lsum *= sc;
#pragma unroll
        for (int nt = 0; nt < 8; ++nt)
#pragma unroll
          for (int i = 0; i < 4; ++i) acc[nt][i] *= sc;
      }
      float rs = 0.f;
#pragma unroll
      for (int kh = 0; kh < 4; ++kh)
#pragma unroll
        for (int i = 0; i < 4; ++i) {
          float p = __expf(pv[kh][i] - m);
          pv[kh][i] = p;
          rs += p;
        }
      rs += __shfl_xor(rs, 16);
      rs += __shfl_xor(rs, 32);
      lsum += rs;
      // ---- pack P -> per-wave LDS [16 q][64 k] ----
      u16* pw = plds[w];
#pragma unroll
      for (int kh = 0; kh < 4; ++kh) {
        unsigned int d0 = (unsigned int)f2bf(pv[kh][0]) | ((unsigned int)f2bf(pv[kh][1]) << 16);
        unsigned int d1 = (unsigned int)f2bf(pv[kh][2]) | ((unsigned int)f2bf(pv[kh][3]) << 16);
        *(unsigned int*)(pw + l15 * 72 + kh * 16 + l4 * 4) = d0;
        *(unsigned int*)(pw + l15 * 72 + kh * 16 + l4 * 4 + 2) = d1;
      }
      bf16x8 pf0 = *(const bf16x8*)(pw + l15 * 72 + l4 * 8);
      bf16x8 pf1 = *(const bf16x8*)(pw + l15 * 72 + 32 + l4 * 8);
      // ---- PV: O^T += V^T * P^T (A = V^T from LDS, B = P), 2 K=32 halves ----
      __builtin_amdgcn_s_setprio(1);
#pragma unroll
      for (int nt = 0; nt < 8; ++nt) {
        int d = nt * 16 + l15;
        int ch0 = l4 ^ (d & 7);
        int ch1 = (4 + l4) ^ (d & 7);
        bf16x8 vf0 = *(const bf16x8*)((const char*)vls[buf] + d * 128 + ch0 * 16);
        bf16x8 vf1 = *(const bf16x8*)((const char*)vls[buf] + d * 128 + ch1 * 16);
        acc[nt] = __builtin_amdgcn_mfma_f32_16x16x32_bf16(vf0, pf0, acc[nt], 0, 0, 0);
        acc[nt] = __builtin_amdgcn_mfma_f32_16x16x32_bf16(vf1, pf1, acc[nt], 0, 0, 0);
      }
      __builtin_amdgcn_s_setprio(0);
    }
    __builtin_amdgcn_sched_barrier(0);
    __builtin_amdgcn_s_barrier();
    buf ^= 1;
  }

  // ---- epilogue ----
  float inv = 1.0f / lsum;
#pragma unroll
  for (int nt = 0; nt < 8; ++nt) {
    u16x4 o;
#pragma unroll
    for (int i = 0; i < 4; ++i) o[i] = f2bf(acc[nt][i] * inv);
    *(u16x4*)(O + (size_t)(wq0 + l15) * (NQ * DH) + h * DH + nt * 16 + l4 * 4) = o;
  }
}

extern "C" void kernel_launch(void* const* d_in, const int* in_sizes, int n_in,
                              void* d_out, int out_size, void* d_ws, size_t ws_size,
                              hipStream_t stream) {
  const float* hidden = (const float*)d_in[0];
  const float* cosb   = (const float*)d_in[1];
  const float* sinb   = (const float*)d_in[2];
  const float* w_qkv  = (const float*)d_in[3];
  const float* qnw    = (const float*)d_in[4];
  const float* knw    = (const float*)d_in[5];
  const float* w_o    = (const float*)d_in[6];
  float* out = (float*)d_out;
  char* ws = (char*)d_ws;

  u16*   wqkvT  = (u16*)(ws);                        // [0, 48M)
  u16*   hid_bf = (u16*)(ws + ((size_t)48 << 20));   // [48M, 64M)
  u16*   qkv_bf = (u16*)(ws + ((size_t)64 << 20));   // [64M, 88M) bf16 qkv (24MB)
  u16*   q_bf   = (u16*)(ws + ((size_t)112 << 20));  // 16MB
  u16*   k_bf   = (u16*)(ws + ((size_t)128 << 20));  // 4MB
  u16*   vt_bf  = (u16*)(ws + ((size_t)132 << 20));  // 4MB
  u16*   attn_bf= (u16*)(ws + ((size_t)48 << 20));   // reuse hid_bf region
  u16*   woT    = (u16*)(ws);                        // reuse wqkvT region

  f32_to_bf16<<<4096, 256, 0, stream>>>(hidden, hid_bf, T_SEQ * HID);
  transpose_f32_to_bf16<<<dim3(96, 64), dim3(16, 16), 0, stream>>>(w_qkv, wqkvT, HID, 6144);
  // gemm1: 2048x6144x4096, BN=192 -> grid 8x32 = 256 blocks (full fill), bf16 out
  gemm_2w<3, true><<<256, 512, 0, stream>>>(hid_bf, wqkvT, qkv_bf, 6144, HID, 64);
  transpose_f32_to_bf16<<<dim3(64, 64), dim3(16, 16), 0, stream>>>(w_o, woT, NQ * DH, HID);
  rope_kernel<<<(T_SEQ * 48) / 4, 256, 0, stream>>>(qkv_bf, cosb, sinb, qnw, knw, q_bf, k_bf, vt_bf);
  attn_kernel<<<dim3(NQ, T_SEQ / 64), 256, 0, stream>>>(q_bf, k_bf, vt_bf, attn_bf);
  // gemm2: 2048x4096x4096, one-ahead pipelined, grid 8x32 = 256 (full fill), f32 out
  gemm2_p<<<256, 512, 0, stream>>>(attn_bf, woT, out, HID, NQ * DH, 64);
}

// Round 15
// 319.136 us; speedup vs baseline: 1.0362x; 1.0362x over previous
//
#include <hip/hip_runtime.h>
#include <hip/hip_bf16.h>

typedef unsigned short u16;
typedef __attribute__((ext_vector_type(8))) short bf16x8;
typedef __attribute__((ext_vector_type(4))) float f32x4;
typedef __attribute__((ext_vector_type(8))) u16 u16x8;
typedef __attribute__((ext_vector_type(4))) u16 u16x4;

#define T_SEQ 2048
#define HID 4096
#define NQ 32
#define NKV 8
#define DH 128
#define WIN 1024

__device__ __forceinline__ u16 f2bf(float f) {
  union { float f; unsigned int u; } v; v.f = f;
  unsigned int u = v.u;
  unsigned int r = (u + 0x7FFFu + ((u >> 16) & 1u)) >> 16;
  return (u16)r;
}
__device__ __forceinline__ float bf2f(u16 b) {
  union { unsigned int u; float f; } v; v.u = ((unsigned int)b) << 16;
  return v.f;
}

__device__ __forceinline__ void gload16(const void* g, void* l) {
  __builtin_amdgcn_global_load_lds(
      (const __attribute__((address_space(1))) unsigned int*)g,
      (__attribute__((address_space(3))) unsigned int*)l, 16, 0, 0);
}

// ---------------- elementwise f32 -> bf16 ----------------
__global__ __launch_bounds__(256) void f32_to_bf16(const float* __restrict__ in,
                                                   u16* __restrict__ out, int n) {
  int i = (blockIdx.x * 256 + threadIdx.x) * 8;
  if (i >= n) return;
  float4 a = *(const float4*)(in + i);
  float4 b = *(const float4*)(in + i + 4);
  u16x8 r;
  r[0] = f2bf(a.x); r[1] = f2bf(a.y); r[2] = f2bf(a.z); r[3] = f2bf(a.w);
  r[4] = f2bf(b.x); r[5] = f2bf(b.y); r[6] = f2bf(b.z); r[7] = f2bf(b.w);
  *(u16x8*)(out + i) = r;
}

// ---------------- tiled transpose f32 (R x C) -> bf16 (C x R), 64x64 float4 ----------------
__global__ __launch_bounds__(256) void transpose_f32_to_bf16(const float* __restrict__ in,
                                                             u16* __restrict__ out,
                                                             int R, int C) {
  __shared__ float tile[64][65];
  int c0 = blockIdx.x * 64, r0 = blockIdx.y * 64;
  int tx = threadIdx.x, ty = threadIdx.y;    // 16 x 16
#pragma unroll
  for (int i = 0; i < 64; i += 16) {
    float4 v = *(const float4*)(in + (size_t)(r0 + ty + i) * C + c0 + tx * 4);
    tile[ty + i][tx * 4 + 0] = v.x;
    tile[ty + i][tx * 4 + 1] = v.y;
    tile[ty + i][tx * 4 + 2] = v.z;
    tile[ty + i][tx * 4 + 3] = v.w;
  }
  __syncthreads();
#pragma unroll
  for (int i = 0; i < 64; i += 16) {
    u16x4 o;
#pragma unroll
    for (int j = 0; j < 4; ++j) o[j] = f2bf(tile[tx * 4 + j][ty + i]);
    *(u16x4*)(out + (size_t)(c0 + ty + i) * R + r0 + tx * 4) = o;
  }
}

// ---------------- gemm_3s: 256xBN 2-window GEMM, 3-slot A ring (deep A lead) ----------------
// Identical to gemm_2w except A staging leads by 2 tiles (ring of 3 slots):
// W1(t): rd afA(mh0)[slot t%3] + ALL B frags[slot t&1] | stage A(t+2)->slot
//        (t+2)%3 | barrier | lgkm0 | MFMA mh0 x all | barrier
// W2(t): rd afB(mh1)[slot t%3] | stage B(t+2)->slot t&1 | barrier | lgkm0 |
//        MFMA mh1 x all | vmcnt(4+NB) | barrier
// vmcnt ledger: outstanding at wait = A(t+1)4 + B(t+1)NB + A(t+2)4 + B(t+2)NB;
// vmcnt(4+NB) retires A(t+1)+B(t+1). A lead = 4 windows (~2 tiles, covers
// ~900cy HBM-miss latency); B lead unchanged (2 tiles).
// Slot hazards: A slot (t+2)%3 last read by tile t-1 (same mod-3), drained
// >=1 barrier before W1(t) stage; B(t) slot t&1 last read W1(t), staged W2(t).
// Tail: kt clamps to NT-1 (dummies keep counts exact; dummy slots never read).
// LDS: A 3x(256*64*2B)=96KB + B 2x(BN*64*2B). NF=3: 144KB (1 block/CU).
template <int NF, bool BF16OUT>
__global__ __launch_bounds__(512, 2) void gemm_3s(const u16* __restrict__ A,
                                                  const u16* __restrict__ Bt,
                                                  void* __restrict__ Cv,
                                                  int N, int K, int NT) {
  constexpr int HN = NF * 16;
  constexpr int BN = 4 * HN;
  constexpr int NB = BN / 64;
  __shared__ u16 lsA[3][16384];
  __shared__ u16 lsB[2][BN * 64];
  const int tid = threadIdx.x;
  const int lane = tid & 63, w = tid >> 6;
  const int wm = w >> 1, wn = w & 1;
  const int l15 = lane & 15, l4 = lane >> 4;

  const int nwg = gridDim.x;
  const int cpx = nwg >> 3;
  const int bid = blockIdx.x;
  const int swz = (bid & 7) * cpx + (bid >> 3);
  const int bm = (swz & 7) * 256;
  const int bn = (swz >> 3) * BN;

  auto stageA = [&](int unit, int slot, int kt) {
    int r = tid >> 3, cp = tid & 7;
    int scp = cp ^ (r & 7);
    gload16(A + (size_t)(bm + unit * 64 + r) * K + kt * 64 + scp * 8,
            (char*)lsA[slot] + (unit * 512 + tid) * 16);
  };
  auto stageB = [&](int unit, int slot, int kt) {
    int r = tid >> 3, cp = tid & 7;
    int scp = cp ^ (r & 7);
    gload16(Bt + (size_t)(bn + unit * 64 + r) * K + kt * 64 + scp * 8,
            (char*)lsB[slot] + (unit * 512 + tid) * 16);
  };
  auto rdA = [&](int slot, int mh, int mf, int ks) -> bf16x8 {
    int r = wm * 64 + mh * 32 + mf * 16 + l15;
    int ch = (ks * 4 + l4) ^ (r & 7);
    return *(const bf16x8*)(lsA[slot] + r * 64 + ch * 8);
  };
  auto rdB = [&](int slot, int nh, int nf, int ks) -> bf16x8 {
    int r = wn * 2 * HN + nh * HN + nf * 16 + l15;
    int ch = (ks * 4 + l4) ^ (r & 7);
    return *(const bf16x8*)(lsB[slot] + r * 64 + ch * 8);
  };

#define WAIT_AB() do { if constexpr (NB == 3) asm volatile("s_waitcnt vmcnt(7)" ::: "memory"); \
                       else                   asm volatile("s_waitcnt vmcnt(6)" ::: "memory"); } while (0)

  f32x4 acc[4][2 * NF] = {};
  bf16x8 afA[2][2], afB[2][2], bfr[2 * NF][2];

  // prologue: A(0)s0 B(0)s0 A(1)s1 B(1)s1; vmcnt(4+NB) -> tile0 resident
  stageA(0, 0, 0); stageA(1, 0, 0); stageA(2, 0, 0); stageA(3, 0, 0);
#pragma unroll
  for (int u = 0; u < NB; ++u) stageB(u, 0, 0);
  stageA(0, 1, 1); stageA(1, 1, 1); stageA(2, 1, 1); stageA(3, 1, 1);
#pragma unroll
  for (int u = 0; u < NB; ++u) stageB(u, 1, 1);
  WAIT_AB();
  __builtin_amdgcn_s_barrier();

  for (int t = 0; t < NT; ++t) {
    const int s3 = t % 3;
    const int s3s = (t + 2) % 3;
    const int s2 = t & 1;
    const int ktt = (t + 2 < NT) ? t + 2 : NT - 1;

    // ---- W1 ----
#pragma unroll
    for (int mf = 0; mf < 2; ++mf)
#pragma unroll
      for (int ks = 0; ks < 2; ++ks) afA[mf][ks] = rdA(s3, 0, mf, ks);
#pragma unroll
    for (int nf = 0; nf < NF; ++nf)
#pragma unroll
      for (int ks = 0; ks < 2; ++ks) {
        bfr[nf][ks] = rdB(s2, 0, nf, ks);
        bfr[NF + nf][ks] = rdB(s2, 1, nf, ks);
      }
    stageA(0, s3s, ktt); stageA(1, s3s, ktt);
    stageA(2, s3s, ktt); stageA(3, s3s, ktt);
    __builtin_amdgcn_s_barrier();
    asm volatile("s_waitcnt lgkmcnt(0)" ::: "memory");
    __builtin_amdgcn_sched_barrier(0);
    __builtin_amdgcn_s_setprio(1);
#pragma unroll
    for (int mf = 0; mf < 2; ++mf)
#pragma unroll
      for (int nf = 0; nf < 2 * NF; ++nf) {
        acc[mf][nf] = __builtin_amdgcn_mfma_f32_16x16x32_bf16(afA[mf][0], bfr[nf][0], acc[mf][nf], 0, 0, 0);
        acc[mf][nf] = __builtin_amdgcn_mfma_f32_16x16x32_bf16(afA[mf][1], bfr[nf][1], acc[mf][nf], 0, 0, 0);
      }
    __builtin_amdgcn_s_setprio(0);
    __builtin_amdgcn_s_barrier();

    // ---- W2 ----
#pragma unroll
    for (int mf = 0; mf < 2; ++mf)
#pragma unroll
      for (int ks = 0; ks < 2; ++ks) afB[mf][ks] = rdA(s3, 1, mf, ks);
#pragma unroll
    for (int u = 0; u < NB; ++u) stageB(u, s2, ktt);
    __builtin_amdgcn_s_barrier();
    asm volatile("s_waitcnt lgkmcnt(0)" ::: "memory");
    __builtin_amdgcn_sched_barrier(0);
    __builtin_amdgcn_s_setprio(1);
#pragma unroll
    for (int mf = 0; mf < 2; ++mf)
#pragma unroll
      for (int nf = 0; nf < 2 * NF; ++nf) {
        acc[2 + mf][nf] = __builtin_amdgcn_mfma_f32_16x16x32_bf16(afB[mf][0], bfr[nf][0], acc[2 + mf][nf], 0, 0, 0);
        acc[2 + mf][nf] = __builtin_amdgcn_mfma_f32_16x16x32_bf16(afB[mf][1], bfr[nf][1], acc[2 + mf][nf], 0, 0, 0);
      }
    __builtin_amdgcn_s_setprio(0);
    WAIT_AB();
    __builtin_amdgcn_s_barrier();
  }

  asm volatile("s_waitcnt vmcnt(0)" ::: "memory");

#pragma unroll
  for (int mi = 0; mi < 4; ++mi)
#pragma unroll
    for (int ni = 0; ni < 2 * NF; ++ni) {
      int row = bm + wm * 64 + mi * 16 + l4 * 4;
      int col = bn + wn * 2 * HN + ni * 16 + l15;
      if constexpr (BF16OUT) {
        u16* dst = (u16*)Cv;
#pragma unroll
        for (int j = 0; j < 4; ++j)
          dst[(size_t)(row + j) * N + col] = f2bf(acc[mi][ni][j]);
      } else {
        float* p = (float*)Cv + (size_t)row * N + col;
        p[0] = acc[mi][ni][0];
        p[(size_t)N] = acc[mi][ni][1];
        p[2 * (size_t)N] = acc[mi][ni][2];
        p[3 * (size_t)N] = acc[mi][ni][3];
      }
    }
#undef WAIT_AB
}

// ---------------- 256xBN 2-window full-fill GEMM (R12-proven, used for gemm2) ----------------
// W1: rd afA(mh0) + ALL B frags | stage A(t+1) u0..3 [slot^1] | barrier |
//     lgkm0 | MFMA mh0 x all nf | barrier
// W2: rd afB(mh1) | stage B(t+2) u0..NB-1 [slot] | barrier | lgkm0 |
//     MFMA mh1 x all nf | vmcnt(NB) | barrier
template <int NF, bool BF16OUT>
__global__ __launch_bounds__(512, 2) void gemm_2w(const u16* __restrict__ A,
                                                  const u16* __restrict__ Bt,
                                                  void* __restrict__ Cv,
                                                  int N, int K, int NT) {
  constexpr int HN = NF * 16;
  constexpr int BN = 4 * HN;
  constexpr int NB = BN / 64;
  __shared__ u16 lsA[2][16384];
  __shared__ u16 lsB[2][BN * 64];
  const int tid = threadIdx.x;
  const int lane = tid & 63, w = tid >> 6;
  const int wm = w >> 1, wn = w & 1;
  const int l15 = lane & 15, l4 = lane >> 4;

  const int nwg = gridDim.x;
  const int cpx = nwg >> 3;
  const int bid = blockIdx.x;
  const int swz = (bid & 7) * cpx + (bid >> 3);
  const int bm = (swz & 7) * 256;
  const int bn = (swz >> 3) * BN;

  auto stageA = [&](int unit, int slot, int kt) {
    int r = tid >> 3, cp = tid & 7;
    int scp = cp ^ (r & 7);
    gload16(A + (size_t)(bm + unit * 64 + r) * K + kt * 64 + scp * 8,
            (char*)lsA[slot] + (unit * 512 + tid) * 16);
  };
  auto stageB = [&](int unit, int slot, int kt) {
    int r = tid >> 3, cp = tid & 7;
    int scp = cp ^ (r & 7);
    gload16(Bt + (size_t)(bn + unit * 64 + r) * K + kt * 64 + scp * 8,
            (char*)lsB[slot] + (unit * 512 + tid) * 16);
  };
  auto rdA = [&](int slot, int mh, int mf, int ks) -> bf16x8 {
    int r = wm * 64 + mh * 32 + mf * 16 + l15;
    int ch = (ks * 4 + l4) ^ (r & 7);
    return *(const bf16x8*)(lsA[slot] + r * 64 + ch * 8);
  };
  auto rdB = [&](int slot, int nh, int nf, int ks) -> bf16x8 {
    int r = wn * 2 * HN + nh * HN + nf * 16 + l15;
    int ch = (ks * 4 + l4) ^ (r & 7);
    return *(const bf16x8*)(lsB[slot] + r * 64 + ch * 8);
  };

#define WAIT_NB() do { if constexpr (NB == 3) asm volatile("s_waitcnt vmcnt(3)" ::: "memory"); \
                       else                   asm volatile("s_waitcnt vmcnt(2)" ::: "memory"); } while (0)

  f32x4 acc[4][2 * NF] = {};
  bf16x8 afA[2][2], afB[2][2], bfr[2 * NF][2];

  stageA(0, 0, 0); stageA(1, 0, 0); stageA(2, 0, 0); stageA(3, 0, 0);
#pragma unroll
  for (int u = 0; u < NB; ++u) stageB(u, 0, 0);
#pragma unroll
  for (int u = 0; u < NB; ++u) stageB(u, 1, 1);
  WAIT_NB();
  __builtin_amdgcn_s_barrier();

  for (int t = 0; t < NT; ++t) {
    const int s = t & 1;
    const int ktA = (t + 1 < NT) ? t + 1 : NT - 1;
    const int ktB = (t + 2 < NT) ? t + 2 : NT - 1;

    // ---- W1 ----
#pragma unroll
    for (int mf = 0; mf < 2; ++mf)
#pragma unroll
      for (int ks = 0; ks < 2; ++ks) afA[mf][ks] = rdA(s, 0, mf, ks);
#pragma unroll
    for (int nf = 0; nf < NF; ++nf)
#pragma unroll
      for (int ks = 0; ks < 2; ++ks) {
        bfr[nf][ks] = rdB(s, 0, nf, ks);
        bfr[NF + nf][ks] = rdB(s, 1, nf, ks);
      }
    stageA(0, s ^ 1, ktA); stageA(1, s ^ 1, ktA);
    stageA(2, s ^ 1, ktA); stageA(3, s ^ 1, ktA);
    __builtin_amdgcn_s_barrier();
    asm volatile("s_waitcnt lgkmcnt(0)" ::: "memory");
    __builtin_amdgcn_sched_barrier(0);
    __builtin_amdgcn_s_setprio(1);
#pragma unroll
    for (int mf = 0; mf < 2; ++mf)
#pragma unroll
      for (int nf = 0; nf < 2 * NF; ++nf) {
        acc[mf][nf] = __builtin_amdgcn_mfma_f32_16x16x32_bf16(afA[mf][0], bfr[nf][0], acc[mf][nf], 0, 0, 0);
        acc[mf][nf] = __builtin_amdgcn_mfma_f32_16x16x32_bf16(afA[mf][1], bfr[nf][1], acc[mf][nf], 0, 0, 0);
      }
    __builtin_amdgcn_s_setprio(0);
    __builtin_amdgcn_s_barrier();

    // ---- W2 ----
#pragma unroll
    for (int mf = 0; mf < 2; ++mf)
#pragma unroll
      for (int ks = 0; ks < 2; ++ks) afB[mf][ks] = rdA(s, 1, mf, ks);
#pragma unroll
    for (int u = 0; u < NB; ++u) stageB(u, s, ktB);
    __builtin_amdgcn_s_barrier();
    asm volatile("s_waitcnt lgkmcnt(0)" ::: "memory");
    __builtin_amdgcn_sched_barrier(0);
    __builtin_amdgcn_s_setprio(1);
#pragma unroll
    for (int mf = 0; mf < 2; ++mf)
#pragma unroll
      for (int nf = 0; nf < 2 * NF; ++nf) {
        acc[2 + mf][nf] = __builtin_amdgcn_mfma_f32_16x16x32_bf16(afB[mf][0], bfr[nf][0], acc[2 + mf][nf], 0, 0, 0);
        acc[2 + mf][nf] = __builtin_amdgcn_mfma_f32_16x16x32_bf16(afB[mf][1], bfr[nf][1], acc[2 + mf][nf], 0, 0, 0);
      }
    __builtin_amdgcn_s_setprio(0);
    WAIT_NB();
    __builtin_amdgcn_s_barrier();
  }

  asm volatile("s_waitcnt vmcnt(0)" ::: "memory");

#pragma unroll
  for (int mi = 0; mi < 4; ++mi)
#pragma unroll
    for (int ni = 0; ni < 2 * NF; ++ni) {
      int row = bm + wm * 64 + mi * 16 + l4 * 4;
      int col = bn + wn * 2 * HN + ni * 16 + l15;
      if constexpr (BF16OUT) {
        u16* dst = (u16*)Cv;
#pragma unroll
        for (int j = 0; j < 4; ++j)
          dst[(size_t)(row + j) * N + col] = f2bf(acc[mi][ni][j]);
      } else {
        float* p = (float*)Cv + (size_t)row * N + col;
        p[0] = acc[mi][ni][0];
        p[(size_t)N] = acc[mi][ni][1];
        p[2 * (size_t)N] = acc[mi][ni][2];
        p[3 * (size_t)N] = acc[mi][ni][3];
      }
    }
#undef WAIT_NB
}

// ---------------- RMSNorm + RoPE + layout (bf16 qkv in; Q scaled; V transposed) -------
__global__ __launch_bounds__(256) void rope_kernel(const u16* __restrict__ qkv,
                                                   const float* __restrict__ cosb,
                                                   const float* __restrict__ sinb,
                                                   const float* __restrict__ qw,
                                                   const float* __restrict__ kw,
                                                   u16* __restrict__ Qo,
                                                   u16* __restrict__ Ko,
                                                   u16* __restrict__ Vt) {
  int wid = threadIdx.x >> 6, lane = threadIdx.x & 63;
  int item = blockIdx.x * 4 + wid;          // item = t*48 + hid
  int t = item / 48, hid = item % 48;
  const u16* x = qkv + (size_t)t * 6144 + hid * 128;
  float x1 = bf2f(x[lane]), x2 = bf2f(x[lane + 64]);
  if (hid < NQ + NKV) {
    float ss = x1 * x1 + x2 * x2;
    for (int off = 32; off; off >>= 1) ss += __shfl_xor(ss, off);
    float inv = rsqrtf(ss * (1.0f / 128.0f) + 1e-6f);
    const float* wn = (hid < NQ) ? qw : kw;
    float n1 = x1 * inv * wn[lane], n2 = x2 * inv * wn[lane + 64];
    float c1 = cosb[t * 128 + lane], s1 = sinb[t * 128 + lane];
    float c2 = cosb[t * 128 + lane + 64], s2 = sinb[t * 128 + lane + 64];
    float o1 = n1 * c1 - n2 * s1;
    float o2 = n2 * c2 + n1 * s2;
    if (hid < NQ) {
      const float scale = 0.08838834764831845f;  // fold 1/sqrt(128) into Q
      u16* q = Qo + ((size_t)hid * T_SEQ + t) * 128;
      q[lane] = f2bf(o1 * scale); q[lane + 64] = f2bf(o2 * scale);
    } else {
      int h = hid - NQ;
      u16* k = Ko + ((size_t)h * T_SEQ + t) * 128;
      k[lane] = f2bf(o1); k[lane + 64] = f2bf(o2);
    }
  } else {
    int h = hid - (NQ + NKV);
    Vt[((size_t)h * 128 + lane) * T_SEQ + t] = x[lane];
    Vt[((size_t)h * 128 + lane + 64) * T_SEQ + t] = x[lane + 64];
  }
}

// ---------------- flash attention: 4 waves/block, QBLK=64, KVBLK=64 (R11 form) ----------------
__global__ __launch_bounds__(256) void attn_kernel(const u16* __restrict__ Q,
                                                   const u16* __restrict__ Kb,
                                                   const u16* __restrict__ Vt,
                                                   u16* __restrict__ O) {
  __shared__ u16 kls[2][64 * 128];   // 16KB per buf
  __shared__ u16 vls[2][128 * 64];   // 16KB per buf
  __shared__ u16 plds[4][16 * 72];   // per-wave P [16 q][64 k] pad to 72

  const int tid = threadIdx.x;
  const int lane = tid & 63, w = tid >> 6;
  const int l15 = lane & 15, l4 = lane >> 4;
  const int h = blockIdx.x;          // q head
  const int q0 = blockIdx.y * 64;    // block q base
  const int wq0 = q0 + w * 16;       // wave q base
  const int kvh = h >> 2;

  bf16x8 qf[4];
  {
    const u16* qrow = Q + ((size_t)h * T_SEQ + (wq0 + l15)) * DH;
    for (int ks = 0; ks < 4; ++ks)
      qf[ks] = *(const bf16x8*)(qrow + ks * 32 + l4 * 8);
  }

  f32x4 acc[8] = {};
  float m = -1e30f, lsum = 0.f;

  int ks0 = q0 - (WIN - 1); if (ks0 < 0) ks0 = 0;
  ks0 &= ~63;
  const int kend = q0;               // tile [q0, q0+63] covers the diagonal

  auto stage = [&](int b, int k0) {
#pragma unroll
    for (int c = 0; c < 4; ++c) {
      int base = w * 4096 + c * 1024;            // bytes in 16KB tile
      int idx = base / 16 + lane;                // 16B chunk index 0..1023
      {
        int row = idx >> 4;                      // K row (64 rows x 256B)
        int col = (idx & 15) ^ (row & 7);
        gload16(Kb + ((size_t)kvh * T_SEQ + k0 + row) * DH + col * 8,
                (char*)kls[b] + base);
      }
      {
        int d = idx >> 3;                        // V^T row (128 rows x 128B)
        int ch = (idx & 7) ^ (d & 7);
        gload16(Vt + ((size_t)kvh * DH + d) * T_SEQ + k0 + ch * 8,
                (char*)vls[b] + base);
      }
    }
  };

  stage(0, ks0);
  int buf = 0;
  for (int k0 = ks0; k0 <= kend; k0 += 64) {
    bool more = (k0 + 64 <= kend);
    if (more) stage(buf ^ 1, k0 + 64);
    if (more) { asm volatile("s_waitcnt vmcnt(8)" ::: "memory"); }
    else      { asm volatile("s_waitcnt vmcnt(0)" ::: "memory"); }
    __builtin_amdgcn_s_barrier();
    __builtin_amdgcn_sched_barrier(0);

    // wave skip: does [k0, k0+63] intersect [wq0-1023, wq0+15]?
    if (k0 <= wq0 + 15 && k0 + 63 >= wq0 - (WIN - 1)) {
      // ---- QK^T (swapped): S^T[k][q], A=K from LDS, B=Q regs ----
      f32x4 st[4];
      __builtin_amdgcn_s_setprio(1);
#pragma unroll
      for (int kh = 0; kh < 4; ++kh) {
        f32x4 s = {};
        int row = kh * 16 + l15;
        const char* kb = (const char*)kls[buf] + row * 256;
#pragma unroll
        for (int ks = 0; ks < 4; ++ks) {
          int chunk = (ks * 4 + l4) ^ (row & 7);
          bf16x8 kf = *(const bf16x8*)(kb + chunk * 16);
          s = __builtin_amdgcn_mfma_f32_16x16x32_bf16(kf, qf[ks], s, 0, 0, 0);
        }
        st[kh] = s;
      }
      __builtin_amdgcn_s_setprio(0);
      // ---- mask + online softmax (lane owns q = wq0+l15) ----
      const int q = wq0 + l15;
      float pv[4][4];
      float mx = -3e38f;
      // interior: all k in tile allowed for ALL q rows of this wave
      if (k0 + 64 <= wq0 && k0 >= wq0 - 1008) {
#pragma unroll
        for (int kh = 0; kh < 4; ++kh)
#pragma unroll
          for (int i = 0; i < 4; ++i) {
            pv[kh][i] = st[kh][i];
            mx = fmaxf(mx, pv[kh][i]);
          }
      } else {
#pragma unroll
        for (int kh = 0; kh < 4; ++kh)
#pragma unroll
          for (int i = 0; i < 4; ++i) {
            int k = k0 + kh * 16 + l4 * 4 + i;
            bool ok = ((k >> 2) <= (q >> 2)) && (q - k < WIN);
            float s = ok ? st[kh][i] : -3e38f;
            pv[kh][i] = s;
            mx = fmaxf(mx, s);
          }
      }
      mx = fmaxf(mx, __shfl_xor(mx, 16));
      mx = fmaxf(mx, __shfl_xor(mx, 32));
      if (!__all(mx <= m + 8.f)) {      // defer-max
        float mn = fmaxf(m, mx);
        float sc = __expf(m - mn);
        m = mn;
        lsum *= sc;
#pragma unroll
        for (int nt = 0; nt < 8; ++nt)
#pragma unroll
          for (int i = 0; i < 4; ++i) acc[nt][i] *= sc;
      }
      float rs = 0.f;
#pragma unroll
      for (int kh = 0; kh < 4; ++kh)
#pragma unroll
        for (int i = 0; i < 4; ++i) {
          float p = __expf(pv[kh][i] - m);
          pv[kh][i] = p;
          rs += p;
        }
      rs += __shfl_xor(rs, 16);
      rs += __shfl_xor(rs, 32);
      lsum += rs;
      // ---- pack P -> per-wave LDS [16 q][64 k] ----
      u16* pw = plds[w];
#pragma unroll
      for (int kh = 0; kh < 4; ++kh) {
        unsigned int d0 = (unsigned int)f2bf(pv[kh][0]) | ((unsigned int)f2bf(pv[kh][1]) << 16);
        unsigned int d1 = (unsigned int)f2bf(pv[kh][2]) | ((unsigned int)f2bf(pv[kh][3]) << 16);
        *(unsigned int*)(pw + l15 * 72 + kh * 16 + l4 * 4) = d0;
        *(unsigned int*)(pw + l15 * 72 + kh * 16 + l4 * 4 + 2) = d1;
      }
      bf16x8 pf0 = *(const bf16x8*)(pw + l15 * 72 + l4 * 8);
      bf16x8 pf1 = *(const bf16x8*)(pw + l15 * 72 + 32 + l4 * 8);
      // ---- PV: O^T += V^T * P^T (A = V^T from LDS, B = P), 2 K=32 halves ----
      __builtin_amdgcn_s_setprio(1);
#pragma unroll
      for (int nt = 0; nt < 8; ++nt) {
        int d = nt * 16 + l15;
        int ch0 = l4 ^ (d & 7);
        int ch1 = (4 + l4) ^ (d & 7);
        bf16x8 vf0 = *(const bf16x8*)((const char*)vls[buf] + d * 128 + ch0 * 16);
        bf16x8 vf1 = *(const bf16x8*)((const char*)vls[buf] + d * 128 + ch1 * 16);
        acc[nt] = __builtin_amdgcn_mfma_f32_16x16x32_bf16(vf0, pf0, acc[nt], 0, 0, 0);
        acc[nt] = __builtin_amdgcn_mfma_f32_16x16x32_bf16(vf1, pf1, acc[nt], 0, 0, 0);
      }
      __builtin_amdgcn_s_setprio(0);
    }
    __builtin_amdgcn_sched_barrier(0);
    __builtin_amdgcn_s_barrier();
    buf ^= 1;
  }

  // ---- epilogue ----
  float inv = 1.0f / lsum;
#pragma unroll
  for (int nt = 0; nt < 8; ++nt) {
    u16x4 o;
#pragma unroll
    for (int i = 0; i < 4; ++i) o[i] = f2bf(acc[nt][i] * inv);
    *(u16x4*)(O + (size_t)(wq0 + l15) * (NQ * DH) + h * DH + nt * 16 + l4 * 4) = o;
  }
}

extern "C" void kernel_launch(void* const* d_in, const int* in_sizes, int n_in,
                              void* d_out, int out_size, void* d_ws, size_t ws_size,
                              hipStream_t stream) {
  const float* hidden = (const float*)d_in[0];
  const float* cosb   = (const float*)d_in[1];
  const float* sinb   = (const float*)d_in[2];
  const float* w_qkv  = (const float*)d_in[3];
  const float* qnw    = (const float*)d_in[4];
  const float* knw    = (const float*)d_in[5];
  const float* w_o    = (const float*)d_in[6];
  float* out = (float*)d_out;
  char* ws = (char*)d_ws;

  u16*   wqkvT  = (u16*)(ws);                        // [0, 48M)
  u16*   hid_bf = (u16*)(ws + ((size_t)48 << 20));   // [48M, 64M)
  u16*   qkv_bf = (u16*)(ws + ((size_t)64 << 20));   // [64M, 88M) bf16 qkv (24MB)
  u16*   q_bf   = (u16*)(ws + ((size_t)112 << 20));  // 16MB
  u16*   k_bf   = (u16*)(ws + ((size_t)128 << 20));  // 4MB
  u16*   vt_bf  = (u16*)(ws + ((size_t)132 << 20));  // 4MB
  u16*   attn_bf= (u16*)(ws + ((size_t)48 << 20));   // reuse hid_bf region
  u16*   woT    = (u16*)(ws);                        // reuse wqkvT region

  f32_to_bf16<<<4096, 256, 0, stream>>>(hidden, hid_bf, T_SEQ * HID);
  transpose_f32_to_bf16<<<dim3(96, 64), dim3(16, 16), 0, stream>>>(w_qkv, wqkvT, HID, 6144);
  // gemm1: 2048x6144x4096, BN=192, 3-slot A ring (deep A lead), bf16 out
  gemm_3s<3, true><<<256, 512, 0, stream>>>(hid_bf, wqkvT, qkv_bf, 6144, HID, 64);
  transpose_f32_to_bf16<<<dim3(64, 64), dim3(16, 16), 0, stream>>>(w_o, woT, NQ * DH, HID);
  rope_kernel<<<(T_SEQ * 48) / 4, 256, 0, stream>>>(qkv_bf, cosb, sinb, qnw, knw, q_bf, k_bf, vt_bf);
  attn_kernel<<<dim3(NQ, T_SEQ / 64), 256, 0, stream>>>(q_bf, k_bf, vt_bf, attn_bf);
  // gemm2: 2048x4096x4096, BN=128 -> grid 8x32 = 256 (full fill), f32 out (R12-proven)
  gemm_2w<2, false><<<256, 512, 0, stream>>>(attn_bf, woT, out, HID, NQ * DH, 64);
}

// Round 16
// 311.489 us; speedup vs baseline: 1.0616x; 1.0245x over previous
//
#include <hip/hip_runtime.h>
#include <hip/hip_bf16.h>

typedef unsigned short u16;
typedef __attribute__((ext_vector_type(8))) short bf16x8;
typedef __attribute__((ext_vector_type(4))) float f32x4;
typedef __attribute__((ext_vector_type(8))) u16 u16x8;
typedef __attribute__((ext_vector_type(4))) u16 u16x4;

#define T_SEQ 2048
#define HID 4096
#define NQ 32
#define NKV 8
#define DH 128
#define WIN 1024

__device__ __forceinline__ u16 f2bf(float f) {
  union { float f; unsigned int u; } v; v.f = f;
  unsigned int u = v.u;
  unsigned int r = (u + 0x7FFFu + ((u >> 16) & 1u)) >> 16;
  return (u16)r;
}
__device__ __forceinline__ float bf2f(u16 b) {
  union { unsigned int u; float f; } v; v.u = ((unsigned int)b) << 16;
  return v.f;
}

__device__ __forceinline__ void gload16(const void* g, void* l) {
  __builtin_amdgcn_global_load_lds(
      (const __attribute__((address_space(1))) unsigned int*)g,
      (__attribute__((address_space(3))) unsigned int*)l, 16, 0, 0);
}

// ---------------- elementwise f32 -> bf16 ----------------
__global__ __launch_bounds__(256) void f32_to_bf16(const float* __restrict__ in,
                                                   u16* __restrict__ out, int n) {
  int i = (blockIdx.x * 256 + threadIdx.x) * 8;
  if (i >= n) return;
  float4 a = *(const float4*)(in + i);
  float4 b = *(const float4*)(in + i + 4);
  u16x8 r;
  r[0] = f2bf(a.x); r[1] = f2bf(a.y); r[2] = f2bf(a.z); r[3] = f2bf(a.w);
  r[4] = f2bf(b.x); r[5] = f2bf(b.y); r[6] = f2bf(b.z); r[7] = f2bf(b.w);
  *(u16x8*)(out + i) = r;
}

// ---------------- tiled transpose f32 (R x C) -> bf16 (C x R), 64x64 float4 ----------------
__global__ __launch_bounds__(256) void transpose_f32_to_bf16(const float* __restrict__ in,
                                                             u16* __restrict__ out,
                                                             int R, int C) {
  __shared__ float tile[64][65];
  int c0 = blockIdx.x * 64, r0 = blockIdx.y * 64;
  int tx = threadIdx.x, ty = threadIdx.y;    // 16 x 16
#pragma unroll
  for (int i = 0; i < 64; i += 16) {
    float4 v = *(const float4*)(in + (size_t)(r0 + ty + i) * C + c0 + tx * 4);
    tile[ty + i][tx * 4 + 0] = v.x;
    tile[ty + i][tx * 4 + 1] = v.y;
    tile[ty + i][tx * 4 + 2] = v.z;
    tile[ty + i][tx * 4 + 3] = v.w;
  }
  __syncthreads();
#pragma unroll
  for (int i = 0; i < 64; i += 16) {
    u16x4 o;
#pragma unroll
    for (int j = 0; j < 4; ++j) o[j] = f2bf(tile[tx * 4 + j][ty + i]);
    *(u16x4*)(out + (size_t)(c0 + ty + i) * R + r0 + tx * 4) = o;
  }
}

// ---------------- bf16 transpose for V: Vn[2048][1024] -> Vt[1024][2048] ----------------
__global__ __launch_bounds__(256) void v_transpose(const u16* __restrict__ Vn,
                                                   u16* __restrict__ Vt) {
  __shared__ u16 tile[64][68];
  int tx = threadIdx.x & 15, ty = threadIdx.x >> 4;   // 16 x 16
  int t0 = blockIdx.x * 64, dh0 = blockIdx.y * 64;
#pragma unroll
  for (int i = 0; i < 64; i += 16) {
    u16x4 v = *(const u16x4*)(Vn + (size_t)(t0 + ty + i) * 1024 + dh0 + tx * 4);
    tile[ty + i][tx * 4 + 0] = v[0];
    tile[ty + i][tx * 4 + 1] = v[1];
    tile[ty + i][tx * 4 + 2] = v[2];
    tile[ty + i][tx * 4 + 3] = v[3];
  }
  __syncthreads();
#pragma unroll
  for (int i = 0; i < 64; i += 16) {
    u16x4 o;
#pragma unroll
    for (int j = 0; j < 4; ++j) o[j] = tile[tx * 4 + j][ty + i];
    *(u16x4*)(Vt + (size_t)(dh0 + ty + i) * 2048 + t0 + tx * 4) = o;
  }
}

// ---------------- gemm_1w: 256xBN GEMM, ONE barrier per K-tile ----------------
// C(MxN) = A(bf16 MxK rm) * Bt(bf16 NxK rm)^T.  BM=256, BN=NF*64, BK=64.
// 8 waves 4Mx2N (per-wave 64 x 2HN).  A 2-slot (64KB), B 3-ring (3xBN*128B).
// Window(t): rd afA[4] (slot t&1) + bfr[2NF] (slot t%3) | stage A(t+1)->slot
//   (t+1)&1 | stage B(t+2)->slot (t+2)%3 | lgkm0 | sched_barrier | setprio |
//   4*2NF*2 MFMA | vmcnt(NB) | s_barrier.
// Safety: barrier is collective -> skew <= 1 window; within a window all waves
//   read slots {t&1, t%3} and stage into {(t+1)&1, (t+2)%3} -- disjoint.
//   Own ds_reads drain at lgkm0 before end barrier; stages into a slot occur
//   >=1 barrier after its last reader's window ends.
// vmcnt: W(t) issues A(t+1)x4 then B(t+2)xNB; vmcnt(NB) retires everything
//   older (incl. A(t+1), B(t+1)) leaving B(t+2) flying. Prologue: A0,B0,B1
//   then vmcnt(NB) -> tile0 resident, B1 flying. Tail: kt clamps to NT-1;
//   dummy stages land in slots never read again. Final vmcnt(0).
// Swizzle chunk ^= row&7 (128B rows), pre-swizzled source (both sides).
template <int NF, bool BF16OUT>
__global__ __launch_bounds__(512, 2) void gemm_1w(const u16* __restrict__ A,
                                                  const u16* __restrict__ Bt,
                                                  void* __restrict__ Cv,
                                                  int N, int K, int NT) {
  constexpr int HN = NF * 16;
  constexpr int BN = 4 * HN;
  constexpr int NB = BN / 64;
  __shared__ u16 lsA[2][16384];     // 2 x 32KB
  __shared__ u16 lsB[3][BN * 64];   // 3 x (BN*128B)
  const int tid = threadIdx.x;
  const int lane = tid & 63, w = tid >> 6;
  const int wm = w >> 1, wn = w & 1;           // 4M x 2N
  const int l15 = lane & 15, l4 = lane >> 4;

  const int nwg = gridDim.x;
  const int cpx = nwg >> 3;
  const int bid = blockIdx.x;
  const int swz = (bid & 7) * cpx + (bid >> 3);
  const int bm = (swz & 7) * 256;
  const int bn = (swz >> 3) * BN;

  auto stageA = [&](int unit, int slot, int kt) {
    int r = tid >> 3, cp = tid & 7;
    int scp = cp ^ (r & 7);
    gload16(A + (size_t)(bm + unit * 64 + r) * K + kt * 64 + scp * 8,
            (char*)lsA[slot] + (unit * 512 + tid) * 16);
  };
  auto stageB = [&](int unit, int slot, int kt) {
    int r = tid >> 3, cp = tid & 7;
    int scp = cp ^ (r & 7);
    gload16(Bt + (size_t)(bn + unit * 64 + r) * K + kt * 64 + scp * 8,
            (char*)lsB[slot] + (unit * 512 + tid) * 16);
  };
  auto rdA = [&](int slot, int mf, int ks) -> bf16x8 {
    int r = wm * 64 + mf * 16 + l15;
    int ch = (ks * 4 + l4) ^ (r & 7);
    return *(const bf16x8*)(lsA[slot] + r * 64 + ch * 8);
  };
  auto rdB = [&](int slot, int nf, int ks) -> bf16x8 {
    int r = wn * 2 * HN + nf * 16 + l15;
    int ch = (ks * 4 + l4) ^ (r & 7);
    return *(const bf16x8*)(lsB[slot] + r * 64 + ch * 8);
  };

#define WAIT_NB() do { if constexpr (NB == 3) asm volatile("s_waitcnt vmcnt(3)" ::: "memory"); \
                       else                   asm volatile("s_waitcnt vmcnt(2)" ::: "memory"); } while (0)

  f32x4 acc[4][2 * NF] = {};
  bf16x8 afA[4][2], bfr[2 * NF][2];

  // prologue: A(0)->s0, B(0)->s0, B(1)->s1; vmcnt(NB) -> tile0 resident
  stageA(0, 0, 0); stageA(1, 0, 0); stageA(2, 0, 0); stageA(3, 0, 0);
#pragma unroll
  for (int u = 0; u < NB; ++u) stageB(u, 0, 0);
#pragma unroll
  for (int u = 0; u < NB; ++u) stageB(u, 1, 1);
  WAIT_NB();
  __builtin_amdgcn_s_barrier();

  for (int t = 0; t < NT; ++t) {
    const int sA = t & 1, sB = t % 3;
    const int ktA = (t + 1 < NT) ? t + 1 : NT - 1;
    const int ktB = (t + 2 < NT) ? t + 2 : NT - 1;

    // reads (tile t)
#pragma unroll
    for (int mf = 0; mf < 4; ++mf)
#pragma unroll
      for (int ks = 0; ks < 2; ++ks) afA[mf][ks] = rdA(sA, mf, ks);
#pragma unroll
    for (int nf = 0; nf < 2 * NF; ++nf)
#pragma unroll
      for (int ks = 0; ks < 2; ++ks) bfr[nf][ks] = rdB(sB, nf, ks);
    // stages (A one tile ahead, B two tiles ahead)
    stageA(0, (t + 1) & 1, ktA); stageA(1, (t + 1) & 1, ktA);
    stageA(2, (t + 1) & 1, ktA); stageA(3, (t + 1) & 1, ktA);
#pragma unroll
    for (int u = 0; u < NB; ++u) stageB(u, (t + 2) % 3, ktB);
    asm volatile("s_waitcnt lgkmcnt(0)" ::: "memory");
    __builtin_amdgcn_sched_barrier(0);
    __builtin_amdgcn_s_setprio(1);
#pragma unroll
    for (int mf = 0; mf < 4; ++mf)
#pragma unroll
      for (int nf = 0; nf < 2 * NF; ++nf) {
        acc[mf][nf] = __builtin_amdgcn_mfma_f32_16x16x32_bf16(afA[mf][0], bfr[nf][0], acc[mf][nf], 0, 0, 0);
        acc[mf][nf] = __builtin_amdgcn_mfma_f32_16x16x32_bf16(afA[mf][1], bfr[nf][1], acc[mf][nf], 0, 0, 0);
      }
    __builtin_amdgcn_s_setprio(0);
    WAIT_NB();                       // A(t+1)+B(t+1) resident, B(t+2) flying
    __builtin_amdgcn_s_barrier();
  }

  asm volatile("s_waitcnt vmcnt(0)" ::: "memory");   // drain tail dummies

#pragma unroll
  for (int mi = 0; mi < 4; ++mi)
#pragma unroll
    for (int ni = 0; ni < 2 * NF; ++ni) {
      int row = bm + wm * 64 + mi * 16 + l4 * 4;
      int col = bn + wn * 2 * HN + ni * 16 + l15;
      if constexpr (BF16OUT) {
        u16* dst = (u16*)Cv;
#pragma unroll
        for (int j = 0; j < 4; ++j)
          dst[(size_t)(row + j) * N + col] = f2bf(acc[mi][ni][j]);
      } else {
        float* p = (float*)Cv + (size_t)row * N + col;
        p[0] = acc[mi][ni][0];
        p[(size_t)N] = acc[mi][ni][1];
        p[2 * (size_t)N] = acc[mi][ni][2];
        p[3 * (size_t)N] = acc[mi][ni][3];
      }
    }
#undef WAIT_NB
}

// ---------------- RMSNorm + RoPE + layout (bf16 qkv in; Q scaled; V natural) -------
__global__ __launch_bounds__(256) void rope_kernel(const u16* __restrict__ qkv,
                                                   const float* __restrict__ cosb,
                                                   const float* __restrict__ sinb,
                                                   const float* __restrict__ qw,
                                                   const float* __restrict__ kw,
                                                   u16* __restrict__ Qo,
                                                   u16* __restrict__ Ko,
                                                   u16* __restrict__ Vn) {
  int wid = threadIdx.x >> 6, lane = threadIdx.x & 63;
  int item = blockIdx.x * 4 + wid;          // item = t*48 + hid
  int t = item / 48, hid = item % 48;
  const u16* x = qkv + (size_t)t * 6144 + hid * 128;
  float x1 = bf2f(x[lane]), x2 = bf2f(x[lane + 64]);
  if (hid < NQ + NKV) {
    float ss = x1 * x1 + x2 * x2;
    for (int off = 32; off; off >>= 1) ss += __shfl_xor(ss, off);
    float inv = rsqrtf(ss * (1.0f / 128.0f) + 1e-6f);
    const float* wn = (hid < NQ) ? qw : kw;
    float n1 = x1 * inv * wn[lane], n2 = x2 * inv * wn[lane + 64];
    float c1 = cosb[t * 128 + lane], s1 = sinb[t * 128 + lane];
    float c2 = cosb[t * 128 + lane + 64], s2 = sinb[t * 128 + lane + 64];
    float o1 = n1 * c1 - n2 * s1;
    float o2 = n2 * c2 + n1 * s2;
    if (hid < NQ) {
      const float scale = 0.08838834764831845f;  // fold 1/sqrt(128) into Q
      u16* q = Qo + ((size_t)hid * T_SEQ + t) * 128;
      q[lane] = f2bf(o1 * scale); q[lane + 64] = f2bf(o2 * scale);
    } else {
      int h = hid - NQ;
      u16* k = Ko + ((size_t)h * T_SEQ + t) * 128;
      k[lane] = f2bf(o1); k[lane + 64] = f2bf(o2);
    }
  } else {
    int h = hid - (NQ + NKV);
    u16* vn = Vn + (size_t)t * 1024 + h * 128;   // coalesced natural layout
    vn[lane] = x[lane];
    vn[lane + 64] = x[lane + 64];
  }
}

// ---------------- flash attention: 4 waves/block, QBLK=64, KVBLK=64 (R11 form) ----------------
__global__ __launch_bounds__(256) void attn_kernel(const u16* __restrict__ Q,
                                                   const u16* __restrict__ Kb,
                                                   const u16* __restrict__ Vt,
                                                   u16* __restrict__ O) {
  __shared__ u16 kls[2][64 * 128];   // 16KB per buf
  __shared__ u16 vls[2][128 * 64];   // 16KB per buf
  __shared__ u16 plds[4][16 * 72];   // per-wave P [16 q][64 k] pad to 72

  const int tid = threadIdx.x;
  const int lane = tid & 63, w = tid >> 6;
  const int l15 = lane & 15, l4 = lane >> 4;
  const int h = blockIdx.x;          // q head
  const int q0 = blockIdx.y * 64;    // block q base
  const int wq0 = q0 + w * 16;       // wave q base
  const int kvh = h >> 2;

  bf16x8 qf[4];
  {
    const u16* qrow = Q + ((size_t)h * T_SEQ + (wq0 + l15)) * DH;
    for (int ks = 0; ks < 4; ++ks)
      qf[ks] = *(const bf16x8*)(qrow + ks * 32 + l4 * 8);
  }

  f32x4 acc[8] = {};
  float m = -1e30f, lsum = 0.f;

  int ks0 = q0 - (WIN - 1); if (ks0 < 0) ks0 = 0;
  ks0 &= ~63;
  const int kend = q0;               // tile [q0, q0+63] covers the diagonal

  auto stage = [&](int b, int k0) {
#pragma unroll
    for (int c = 0; c < 4; ++c) {
      int base = w * 4096 + c * 1024;            // bytes in 16KB tile
      int idx = base / 16 + lane;                // 16B chunk index 0..1023
      {
        int row = idx >> 4;                      // K row (64 rows x 256B)
        int col = (idx & 15) ^ (row & 7);
        gload16(Kb + ((size_t)kvh * T_SEQ + k0 + row) * DH + col * 8,
                (char*)kls[b] + base);
      }
      {
        int d = idx >> 3;                        // V^T row (128 rows x 128B)
        int ch = (idx & 7) ^ (d & 7);
        gload16(Vt + ((size_t)kvh * DH + d) * T_SEQ + k0 + ch * 8,
                (char*)vls[b] + base);
      }
    }
  };

  stage(0, ks0);
  int buf = 0;
  for (int k0 = ks0; k0 <= kend; k0 += 64) {
    bool more = (k0 + 64 <= kend);
    if (more) stage(buf ^ 1, k0 + 64);
    if (more) { asm volatile("s_waitcnt vmcnt(8)" ::: "memory"); }
    else      { asm volatile("s_waitcnt vmcnt(0)" ::: "memory"); }
    __builtin_amdgcn_s_barrier();
    __builtin_amdgcn_sched_barrier(0);

    // wave skip: does [k0, k0+63] intersect [wq0-1023, wq0+15]?
    if (k0 <= wq0 + 15 && k0 + 63 >= wq0 - (WIN - 1)) {
      // ---- QK^T (swapped): S^T[k][q], A=K from LDS, B=Q regs ----
      f32x4 st[4];
      __builtin_amdgcn_s_setprio(1);
#pragma unroll
      for (int kh = 0; kh < 4; ++kh) {
        f32x4 s = {};
        int row = kh * 16 + l15;
        const char* kb = (const char*)kls[buf] + row * 256;
#pragma unroll
        for (int ks = 0; ks < 4; ++ks) {
          int chunk = (ks * 4 + l4) ^ (row & 7);
          bf16x8 kf = *(const bf16x8*)(kb + chunk * 16);
          s = __builtin_amdgcn_mfma_f32_16x16x32_bf16(kf, qf[ks], s, 0, 0, 0);
        }
        st[kh] = s;
      }
      __builtin_amdgcn_s_setprio(0);
      // ---- mask + online softmax (lane owns q = wq0+l15) ----
      const int q = wq0 + l15;
      float pv[4][4];
      float mx = -3e38f;
      // interior: all k in tile allowed for ALL q rows of this wave
      if (k0 + 64 <= wq0 && k0 >= wq0 - 1008) {
#pragma unroll
        for (int kh = 0; kh < 4; ++kh)
#pragma unroll
          for (int i = 0; i < 4; ++i) {
            pv[kh][i] = st[kh][i];
            mx = fmaxf(mx, pv[kh][i]);
          }
      } else {
#pragma unroll
        for (int kh = 0; kh < 4; ++kh)
#pragma unroll
          for (int i = 0; i < 4; ++i) {
            int k = k0 + kh * 16 + l4 * 4 + i;
            bool ok = ((k >> 2) <= (q >> 2)) && (q - k < WIN);
            float s = ok ? st[kh][i] : -3e38f;
            pv[kh][i] = s;
            mx = fmaxf(mx, s);
          }
      }
      mx = fmaxf(mx, __shfl_xor(mx, 16));
      mx = fmaxf(mx, __shfl_xor(mx, 32));
      if (!__all(mx <= m + 8.f)) {      // defer-max
        float mn = fmaxf(m, mx);
        float sc = __expf(m - mn);
        m = mn;
        lsum *= sc;
#pragma unroll
        for (int nt = 0; nt < 8; ++nt)
#pragma unroll
          for (int i = 0; i < 4; ++i) acc[nt][i] *= sc;
      }
      float rs = 0.f;
#pragma unroll
      for (int kh = 0; kh < 4; ++kh)
#pragma unroll
        for (int i = 0; i < 4; ++i) {
          float p = __expf(pv[kh][i] - m);
          pv[kh][i] = p;
          rs += p;
        }
      rs += __shfl_xor(rs, 16);
      rs += __shfl_xor(rs, 32);
      lsum += rs;
      // ---- pack P -> per-wave LDS [16 q][64 k] ----
      u16* pw = plds[w];
#pragma unroll
      for (int kh = 0; kh < 4; ++kh) {
        unsigned int d0 = (unsigned int)f2bf(pv[kh][0]) | ((unsigned int)f2bf(pv[kh][1]) << 16);
        unsigned int d1 = (unsigned int)f2bf(pv[kh][2]) | ((unsigned int)f2bf(pv[kh][3]) << 16);
        *(unsigned int*)(pw + l15 * 72 + kh * 16 + l4 * 4) = d0;
        *(unsigned int*)(pw + l15 * 72 + kh * 16 + l4 * 4 + 2) = d1;
      }
      bf16x8 pf0 = *(const bf16x8*)(pw + l15 * 72 + l4 * 8);
      bf16x8 pf1 = *(const bf16x8*)(pw + l15 * 72 + 32 + l4 * 8);
      // ---- PV: O^T += V^T * P^T (A = V^T from LDS, B = P), 2 K=32 halves ----
      __builtin_amdgcn_s_setprio(1);
#pragma unroll
      for (int nt = 0; nt < 8; ++nt) {
        int d = nt * 16 + l15;
        int ch0 = l4 ^ (d & 7);
        int ch1 = (4 + l4) ^ (d & 7);
        bf16x8 vf0 = *(const bf16x8*)((const char*)vls[buf] + d * 128 + ch0 * 16);
        bf16x8 vf1 = *(const bf16x8*)((const char*)vls[buf] + d * 128 + ch1 * 16);
        acc[nt] = __builtin_amdgcn_mfma_f32_16x16x32_bf16(vf0, pf0, acc[nt], 0, 0, 0);
        acc[nt] = __builtin_amdgcn_mfma_f32_16x16x32_bf16(vf1, pf1, acc[nt], 0, 0, 0);
      }
      __builtin_amdgcn_s_setprio(0);
    }
    __builtin_amdgcn_sched_barrier(0);
    __builtin_amdgcn_s_barrier();
    buf ^= 1;
  }

  // ---- epilogue ----
  float inv = 1.0f / lsum;
#pragma unroll
  for (int nt = 0; nt < 8; ++nt) {
    u16x4 o;
#pragma unroll
    for (int i = 0; i < 4; ++i) o[i] = f2bf(acc[nt][i] * inv);
    *(u16x4*)(O + (size_t)(wq0 + l15) * (NQ * DH) + h * DH + nt * 16 + l4 * 4) = o;
  }
}

extern "C" void kernel_launch(void* const* d_in, const int* in_sizes, int n_in,
                              void* d_out, int out_size, void* d_ws, size_t ws_size,
                              hipStream_t stream) {
  const float* hidden = (const float*)d_in[0];
  const float* cosb   = (const float*)d_in[1];
  const float* sinb   = (const float*)d_in[2];
  const float* w_qkv  = (const float*)d_in[3];
  const float* qnw    = (const float*)d_in[4];
  const float* knw    = (const float*)d_in[5];
  const float* w_o    = (const float*)d_in[6];
  float* out = (float*)d_out;
  char* ws = (char*)d_ws;

  u16*   wqkvT  = (u16*)(ws);                        // [0, 48M)
  u16*   hid_bf = (u16*)(ws + ((size_t)48 << 20));   // [48M, 64M)
  u16*   qkv_bf = (u16*)(ws + ((size_t)64 << 20));   // [64M, 88M) bf16 qkv (24MB)
  u16*   vn_bf  = (u16*)(ws + ((size_t)88 << 20));   // [88M, 92M) V natural (4MB)
  u16*   q_bf   = (u16*)(ws + ((size_t)112 << 20));  // 16MB
  u16*   k_bf   = (u16*)(ws + ((size_t)128 << 20));  // 4MB
  u16*   vt_bf  = (u16*)(ws + ((size_t)132 << 20));  // 4MB
  u16*   attn_bf= (u16*)(ws + ((size_t)48 << 20));   // reuse hid_bf region
  u16*   woT    = (u16*)(ws);                        // reuse wqkvT region

  f32_to_bf16<<<4096, 256, 0, stream>>>(hidden, hid_bf, T_SEQ * HID);
  transpose_f32_to_bf16<<<dim3(96, 64), dim3(16, 16), 0, stream>>>(w_qkv, wqkvT, HID, 6144);
  // gemm1: 2048x6144x4096, BN=192 -> grid 8x32 = 256 (full fill), bf16 out, 1-barrier/tile
  gemm_1w<3, true><<<256, 512, 0, stream>>>(hid_bf, wqkvT, qkv_bf, 6144, HID, 64);
  transpose_f32_to_bf16<<<dim3(64, 64), dim3(16, 16), 0, stream>>>(w_o, woT, NQ * DH, HID);
  rope_kernel<<<(T_SEQ * 48) / 4, 256, 0, stream>>>(qkv_bf, cosb, sinb, qnw, knw, q_bf, k_bf, vn_bf);
  v_transpose<<<dim3(32, 16), 256, 0, stream>>>(vn_bf, vt_bf);
  attn_kernel<<<dim3(NQ, T_SEQ / 64), 256, 0, stream>>>(q_bf, k_bf, vt_bf, attn_bf);
  // gemm2: 2048x4096x4096, BN=128 -> grid 8x32 = 256 (full fill), f32 out, 1-barrier/tile
  gemm_1w<2, false><<<256, 512, 0, stream>>>(attn_bf, woT, out, HID, NQ * DH, 64);
}

// Round 17
// 303.797 us; speedup vs baseline: 1.0885x; 1.0253x over previous
//
#include <hip/hip_runtime.h>
#include <hip/hip_bf16.h>

typedef unsigned short u16;
typedef __attribute__((ext_vector_type(8))) short bf16x8;
typedef __attribute__((ext_vector_type(4))) float f32x4;
typedef __attribute__((ext_vector_type(8))) u16 u16x8;
typedef __attribute__((ext_vector_type(4))) u16 u16x4;

#define T_SEQ 2048
#define HID 4096
#define NQ 32
#define NKV 8
#define DH 128
#define WIN 1024

__device__ __forceinline__ u16 f2bf(float f) {
  union { float f; unsigned int u; } v; v.f = f;
  unsigned int u = v.u;
  unsigned int r = (u + 0x7FFFu + ((u >> 16) & 1u)) >> 16;
  return (u16)r;
}
__device__ __forceinline__ float bf2f(u16 b) {
  union { unsigned int u; float f; } v; v.u = ((unsigned int)b) << 16;
  return v.f;
}

__device__ __forceinline__ void gload16(const void* g, void* l) {
  __builtin_amdgcn_global_load_lds(
      (const __attribute__((address_space(1))) unsigned int*)g,
      (__attribute__((address_space(3))) unsigned int*)l, 16, 0, 0);
}

// ---------------- elementwise f32 -> bf16 ----------------
__global__ __launch_bounds__(256) void f32_to_bf16(const float* __restrict__ in,
                                                   u16* __restrict__ out, int n) {
  int i = (blockIdx.x * 256 + threadIdx.x) * 8;
  if (i >= n) return;
  float4 a = *(const float4*)(in + i);
  float4 b = *(const float4*)(in + i + 4);
  u16x8 r;
  r[0] = f2bf(a.x); r[1] = f2bf(a.y); r[2] = f2bf(a.z); r[3] = f2bf(a.w);
  r[4] = f2bf(b.x); r[5] = f2bf(b.y); r[6] = f2bf(b.z); r[7] = f2bf(b.w);
  *(u16x8*)(out + i) = r;
}

// ---------------- tiled transpose f32 (R x C) -> bf16 (C x R), 64x64 float4 ----------------
__global__ __launch_bounds__(256) void transpose_f32_to_bf16(const float* __restrict__ in,
                                                             u16* __restrict__ out,
                                                             int R, int C) {
  __shared__ float tile[64][65];
  int c0 = blockIdx.x * 64, r0 = blockIdx.y * 64;
  int tx = threadIdx.x, ty = threadIdx.y;    // 16 x 16
#pragma unroll
  for (int i = 0; i < 64; i += 16) {
    float4 v = *(const float4*)(in + (size_t)(r0 + ty + i) * C + c0 + tx * 4);
    tile[ty + i][tx * 4 + 0] = v.x;
    tile[ty + i][tx * 4 + 1] = v.y;
    tile[ty + i][tx * 4 + 2] = v.z;
    tile[ty + i][tx * 4 + 3] = v.w;
  }
  __syncthreads();
#pragma unroll
  for (int i = 0; i < 64; i += 16) {
    u16x4 o;
#pragma unroll
    for (int j = 0; j < 4; ++j) o[j] = f2bf(tile[tx * 4 + j][ty + i]);
    *(u16x4*)(out + (size_t)(c0 + ty + i) * R + r0 + tx * 4) = o;
  }
}

// ---------------- bf16 transpose for V: Vn[2048][1024] -> Vt[1024][2048] ----------------
__global__ __launch_bounds__(256) void v_transpose(const u16* __restrict__ Vn,
                                                   u16* __restrict__ Vt) {
  __shared__ u16 tile[64][68];
  int tx = threadIdx.x & 15, ty = threadIdx.x >> 4;   // 16 x 16
  int t0 = blockIdx.x * 64, dh0 = blockIdx.y * 64;
#pragma unroll
  for (int i = 0; i < 64; i += 16) {
    u16x4 v = *(const u16x4*)(Vn + (size_t)(t0 + ty + i) * 1024 + dh0 + tx * 4);
    tile[ty + i][tx * 4 + 0] = v[0];
    tile[ty + i][tx * 4 + 1] = v[1];
    tile[ty + i][tx * 4 + 2] = v[2];
    tile[ty + i][tx * 4 + 3] = v[3];
  }
  __syncthreads();
#pragma unroll
  for (int i = 0; i < 64; i += 16) {
    u16x4 o;
#pragma unroll
    for (int j = 0; j < 4; ++j) o[j] = tile[tx * 4 + j][ty + i];
    *(u16x4*)(Vt + (size_t)(dh0 + ty + i) * 2048 + t0 + tx * 4) = o;
  }
}

// ---------------- gemm_1w: 256xBN GEMM, ONE barrier per K-tile (R15-proven, gemm1) ------
// Window(t): rd afA[4](slot t&1) + bfr[2NF](slot t%3) | stage A(t+1)->(t+1)&1 |
//   stage B(t+2)->(t+2)%3 | lgkm0 | setprio | 8NF MFMA | vmcnt(NB) | barrier.
template <int NF, bool BF16OUT>
__global__ __launch_bounds__(512, 2) void gemm_1w(const u16* __restrict__ A,
                                                  const u16* __restrict__ Bt,
                                                  void* __restrict__ Cv,
                                                  int N, int K, int NT) {
  constexpr int HN = NF * 16;
  constexpr int BN = 4 * HN;
  constexpr int NB = BN / 64;
  __shared__ u16 lsA[2][16384];     // 2 x 32KB
  __shared__ u16 lsB[3][BN * 64];   // 3 x (BN*128B)
  const int tid = threadIdx.x;
  const int lane = tid & 63, w = tid >> 6;
  const int wm = w >> 1, wn = w & 1;           // 4M x 2N
  const int l15 = lane & 15, l4 = lane >> 4;

  const int nwg = gridDim.x;
  const int cpx = nwg >> 3;
  const int bid = blockIdx.x;
  const int swz = (bid & 7) * cpx + (bid >> 3);
  const int bm = (swz & 7) * 256;
  const int bn = (swz >> 3) * BN;

  auto stageA = [&](int unit, int slot, int kt) {
    int r = tid >> 3, cp = tid & 7;
    int scp = cp ^ (r & 7);
    gload16(A + (size_t)(bm + unit * 64 + r) * K + kt * 64 + scp * 8,
            (char*)lsA[slot] + (unit * 512 + tid) * 16);
  };
  auto stageB = [&](int unit, int slot, int kt) {
    int r = tid >> 3, cp = tid & 7;
    int scp = cp ^ (r & 7);
    gload16(Bt + (size_t)(bn + unit * 64 + r) * K + kt * 64 + scp * 8,
            (char*)lsB[slot] + (unit * 512 + tid) * 16);
  };
  auto rdA = [&](int slot, int mf, int ks) -> bf16x8 {
    int r = wm * 64 + mf * 16 + l15;
    int ch = (ks * 4 + l4) ^ (r & 7);
    return *(const bf16x8*)(lsA[slot] + r * 64 + ch * 8);
  };
  auto rdB = [&](int slot, int nf, int ks) -> bf16x8 {
    int r = wn * 2 * HN + nf * 16 + l15;
    int ch = (ks * 4 + l4) ^ (r & 7);
    return *(const bf16x8*)(lsB[slot] + r * 64 + ch * 8);
  };

#define WAIT_NB() do { if constexpr (NB == 3) asm volatile("s_waitcnt vmcnt(3)" ::: "memory"); \
                       else                   asm volatile("s_waitcnt vmcnt(2)" ::: "memory"); } while (0)

  f32x4 acc[4][2 * NF] = {};
  bf16x8 afA[4][2], bfr[2 * NF][2];

  stageA(0, 0, 0); stageA(1, 0, 0); stageA(2, 0, 0); stageA(3, 0, 0);
#pragma unroll
  for (int u = 0; u < NB; ++u) stageB(u, 0, 0);
#pragma unroll
  for (int u = 0; u < NB; ++u) stageB(u, 1, 1);
  WAIT_NB();
  __builtin_amdgcn_s_barrier();

  for (int t = 0; t < NT; ++t) {
    const int sA = t & 1, sB = t % 3;
    const int ktA = (t + 1 < NT) ? t + 1 : NT - 1;
    const int ktB = (t + 2 < NT) ? t + 2 : NT - 1;

#pragma unroll
    for (int mf = 0; mf < 4; ++mf)
#pragma unroll
      for (int ks = 0; ks < 2; ++ks) afA[mf][ks] = rdA(sA, mf, ks);
#pragma unroll
    for (int nf = 0; nf < 2 * NF; ++nf)
#pragma unroll
      for (int ks = 0; ks < 2; ++ks) bfr[nf][ks] = rdB(sB, nf, ks);
    stageA(0, (t + 1) & 1, ktA); stageA(1, (t + 1) & 1, ktA);
    stageA(2, (t + 1) & 1, ktA); stageA(3, (t + 1) & 1, ktA);
#pragma unroll
    for (int u = 0; u < NB; ++u) stageB(u, (t + 2) % 3, ktB);
    asm volatile("s_waitcnt lgkmcnt(0)" ::: "memory");
    __builtin_amdgcn_sched_barrier(0);
    __builtin_amdgcn_s_setprio(1);
#pragma unroll
    for (int mf = 0; mf < 4; ++mf)
#pragma unroll
      for (int nf = 0; nf < 2 * NF; ++nf) {
        acc[mf][nf] = __builtin_amdgcn_mfma_f32_16x16x32_bf16(afA[mf][0], bfr[nf][0], acc[mf][nf], 0, 0, 0);
        acc[mf][nf] = __builtin_amdgcn_mfma_f32_16x16x32_bf16(afA[mf][1], bfr[nf][1], acc[mf][nf], 0, 0, 0);
      }
    __builtin_amdgcn_s_setprio(0);
    WAIT_NB();
    __builtin_amdgcn_s_barrier();
  }

  asm volatile("s_waitcnt vmcnt(0)" ::: "memory");

#pragma unroll
  for (int mi = 0; mi < 4; ++mi)
#pragma unroll
    for (int ni = 0; ni < 2 * NF; ++ni) {
      int row = bm + wm * 64 + mi * 16 + l4 * 4;
      int col = bn + wn * 2 * HN + ni * 16 + l15;
      if constexpr (BF16OUT) {
        u16* dst = (u16*)Cv;
#pragma unroll
        for (int j = 0; j < 4; ++j)
          dst[(size_t)(row + j) * N + col] = f2bf(acc[mi][ni][j]);
      } else {
        float* p = (float*)Cv + (size_t)row * N + col;
        p[0] = acc[mi][ni][0];
        p[(size_t)N] = acc[mi][ni][1];
        p[2 * (size_t)N] = acc[mi][ni][2];
        p[3 * (size_t)N] = acc[mi][ni][3];
      }
    }
#undef WAIT_NB
}

// ---------------- gemm_1wh: 128x128 1-window GEMM, 4 waves, 2 blocks/CU (gemm2) --------
// C(f32 2048x4096) = A(bf16) * Bt(bf16)^T. BM=BN=128, BK=64, grid 16x32=512
// (2 blocks/CU; co-resident block covers vmcnt/barrier/LDS-drain stalls, m114).
// 4 waves 2Mx2N (per-wave 64x64 = 4mf x 4nf), 32-MFMA cluster per window.
// LDS 80KB: A 2x16KB, B 3-ring 3x16KB. Stage unit = 4KB (256 thr x 16B);
// A=4 units, B=4 units per tile.
// Window(t): rd afA[4](slot t&1)+bfr[4](slot t%3) | stage A(t+1)->(t+1)&1 x4 |
//   stage B(t+2)->(t+2)%3 x4 | lgkm0 | setprio | 32 MFMA | vmcnt(4) | barrier.
// vmcnt: window-start outstanding = B(t+1)x4; +A(t+1)x4+B(t+2)x4 = 12;
//   vmcnt(4) retires B(t+1)+A(t+1), keeps B(t+2). Prologue A0,B0,B1 (12) +
//   vmcnt(4) -> tile0 resident. Slot hazards: stage target slots {(t+1)&1,
//   (t+2)%3} disjoint from read slots {t&1, t%3}; last readers ended >=1
//   barrier earlier. Tail clamps (dummies); final vmcnt(0).
__global__ __launch_bounds__(256, 2) void gemm_1wh(const u16* __restrict__ A,
                                                   const u16* __restrict__ Bt,
                                                   float* __restrict__ C,
                                                   int N, int K, int NT) {
  __shared__ u16 lsA[2][8192];    // 2 x 16KB (128 rows x 64 k)
  __shared__ u16 lsB[3][8192];    // 3 x 16KB
  const int tid = threadIdx.x;
  const int lane = tid & 63, w = tid >> 6;     // 4 waves
  const int wm = w >> 1, wn = w & 1;           // 2M x 2N
  const int l15 = lane & 15, l4 = lane >> 4;

  const int nwg = gridDim.x;                   // 512, %8==0
  const int cpx = nwg >> 3;
  const int bid = blockIdx.x;
  const int swz = (bid & 7) * cpx + (bid >> 3);
  const int bm = (swz & 15) * 128;             // 16 M-tiles (x-major)
  const int bn = (swz >> 4) * 128;             // 32 N-tiles

  auto stageA = [&](int unit, int slot, int kt) {
    int r = unit * 32 + (tid >> 3), cp = tid & 7;
    int scp = cp ^ (r & 7);
    gload16(A + (size_t)(bm + r) * K + kt * 64 + scp * 8,
            (char*)lsA[slot] + (unit * 256 + tid) * 16);
  };
  auto stageB = [&](int unit, int slot, int kt) {
    int r = unit * 32 + (tid >> 3), cp = tid & 7;
    int scp = cp ^ (r & 7);
    gload16(Bt + (size_t)(bn + r) * K + kt * 64 + scp * 8,
            (char*)lsB[slot] + (unit * 256 + tid) * 16);
  };
  auto rdA = [&](int slot, int mf, int ks) -> bf16x8 {
    int r = wm * 64 + mf * 16 + l15;
    int ch = (ks * 4 + l4) ^ (r & 7);
    return *(const bf16x8*)(lsA[slot] + r * 64 + ch * 8);
  };
  auto rdB = [&](int slot, int nf, int ks) -> bf16x8 {
    int r = wn * 64 + nf * 16 + l15;
    int ch = (ks * 4 + l4) ^ (r & 7);
    return *(const bf16x8*)(lsB[slot] + r * 64 + ch * 8);
  };

  f32x4 acc[4][4] = {};
  bf16x8 afA[4][2], bfr[4][2];

  // prologue: A(0)->s0 x4, B(0)->s0 x4, B(1)->s1 x4; vmcnt(4) -> tile0 resident
#pragma unroll
  for (int u = 0; u < 4; ++u) stageA(u, 0, 0);
#pragma unroll
  for (int u = 0; u < 4; ++u) stageB(u, 0, 0);
#pragma unroll
  for (int u = 0; u < 4; ++u) stageB(u, 1, 1);
  asm volatile("s_waitcnt vmcnt(4)" ::: "memory");
  __builtin_amdgcn_s_barrier();

  for (int t = 0; t < NT; ++t) {
    const int sA = t & 1, sB = t % 3;
    const int ktA = (t + 1 < NT) ? t + 1 : NT - 1;
    const int ktB = (t + 2 < NT) ? t + 2 : NT - 1;

#pragma unroll
    for (int mf = 0; mf < 4; ++mf)
#pragma unroll
      for (int ks = 0; ks < 2; ++ks) afA[mf][ks] = rdA(sA, mf, ks);
#pragma unroll
    for (int nf = 0; nf < 4; ++nf)
#pragma unroll
      for (int ks = 0; ks < 2; ++ks) bfr[nf][ks] = rdB(sB, nf, ks);
#pragma unroll
    for (int u = 0; u < 4; ++u) stageA(u, (t + 1) & 1, ktA);
#pragma unroll
    for (int u = 0; u < 4; ++u) stageB(u, (t + 2) % 3, ktB);
    asm volatile("s_waitcnt lgkmcnt(0)" ::: "memory");
    __builtin_amdgcn_sched_barrier(0);
    __builtin_amdgcn_s_setprio(1);
#pragma unroll
    for (int mf = 0; mf < 4; ++mf)
#pragma unroll
      for (int nf = 0; nf < 4; ++nf) {
        acc[mf][nf] = __builtin_amdgcn_mfma_f32_16x16x32_bf16(afA[mf][0], bfr[nf][0], acc[mf][nf], 0, 0, 0);
        acc[mf][nf] = __builtin_amdgcn_mfma_f32_16x16x32_bf16(afA[mf][1], bfr[nf][1], acc[mf][nf], 0, 0, 0);
      }
    __builtin_amdgcn_s_setprio(0);
    asm volatile("s_waitcnt vmcnt(4)" ::: "memory");   // tile t+1 resident
    __builtin_amdgcn_s_barrier();
  }

  asm volatile("s_waitcnt vmcnt(0)" ::: "memory");

#pragma unroll
  for (int mi = 0; mi < 4; ++mi)
#pragma unroll
    for (int ni = 0; ni < 4; ++ni) {
      int row = bm + wm * 64 + mi * 16 + l4 * 4;
      int col = bn + wn * 64 + ni * 16 + l15;
      float* p = C + (size_t)row * N + col;
      p[0] = acc[mi][ni][0];
      p[(size_t)N] = acc[mi][ni][1];
      p[2 * (size_t)N] = acc[mi][ni][2];
      p[3 * (size_t)N] = acc[mi][ni][3];
    }
}

// ---------------- RMSNorm + RoPE + layout (bf16 qkv in; Q scaled incl log2e; V natural) ----
__global__ __launch_bounds__(256) void rope_kernel(const u16* __restrict__ qkv,
                                                   const float* __restrict__ cosb,
                                                   const float* __restrict__ sinb,
                                                   const float* __restrict__ qw,
                                                   const float* __restrict__ kw,
                                                   u16* __restrict__ Qo,
                                                   u16* __restrict__ Ko,
                                                   u16* __restrict__ Vn) {
  int wid = threadIdx.x >> 6, lane = threadIdx.x & 63;
  int item = blockIdx.x * 4 + wid;          // item = t*48 + hid
  int t = item / 48, hid = item % 48;
  const u16* x = qkv + (size_t)t * 6144 + hid * 128;
  float x1 = bf2f(x[lane]), x2 = bf2f(x[lane + 64]);
  if (hid < NQ + NKV) {
    float ss = x1 * x1 + x2 * x2;
    for (int off = 32; off; off >>= 1) ss += __shfl_xor(ss, off);
    float inv = rsqrtf(ss * (1.0f / 128.0f) + 1e-6f);
    const float* wn = (hid < NQ) ? qw : kw;
    float n1 = x1 * inv * wn[lane], n2 = x2 * inv * wn[lane + 64];
    float c1 = cosb[t * 128 + lane], s1 = sinb[t * 128 + lane];
    float c2 = cosb[t * 128 + lane + 64], s2 = sinb[t * 128 + lane + 64];
    float o1 = n1 * c1 - n2 * s1;
    float o2 = n2 * c2 + n1 * s2;
    if (hid < NQ) {
      // fold 1/sqrt(128) AND log2(e) into Q: softmax runs in log2 domain
      const float scale = 0.08838834764831845f * 1.44269504088896341f;
      u16* q = Qo + ((size_t)hid * T_SEQ + t) * 128;
      q[lane] = f2bf(o1 * scale); q[lane + 64] = f2bf(o2 * scale);
    } else {
      int h = hid - NQ;
      u16* k = Ko + ((size_t)h * T_SEQ + t) * 128;
      k[lane] = f2bf(o1); k[lane + 64] = f2bf(o2);
    }
  } else {
    int h = hid - (NQ + NKV);
    u16* vn = Vn + (size_t)t * 1024 + h * 128;   // coalesced natural layout
    vn[lane] = x[lane];
    vn[lane + 64] = x[lane + 64];
  }
}

// ---------------- flash attention: 4 waves/block, QBLK=64, KVBLK=64 ----------------
// R11 form + log2-domain softmax (exp2, threshold 11.5 = 8*log2e) +
// v_cvt_pk_bf16_f32 for P pack (1 op/pair vs ~6-op manual round).
__global__ __launch_bounds__(256) void attn_kernel(const u16* __restrict__ Q,
                                                   const u16* __restrict__ Kb,
                                                   const u16* __restrict__ Vt,
                                                   u16* __restrict__ O) {
  __shared__ u16 kls[2][64 * 128];   // 16KB per buf
  __shared__ u16 vls[2][128 * 64];   // 16KB per buf
  __shared__ u16 plds[4][16 * 72];   // per-wave P [16 q][64 k] pad to 72

  const int tid = threadIdx.x;
  const int lane = tid & 63, w = tid >> 6;
  const int l15 = lane & 15, l4 = lane >> 4;
  const int h = blockIdx.x;          // q head
  const int q0 = blockIdx.y * 64;    // block q base
  const int wq0 = q0 + w * 16;       // wave q base
  const int kvh = h >> 2;

  bf16x8 qf[4];
  {
    const u16* qrow = Q + ((size_t)h * T_SEQ + (wq0 + l15)) * DH;
    for (int ks = 0; ks < 4; ++ks)
      qf[ks] = *(const bf16x8*)(qrow + ks * 32 + l4 * 8);
  }

  f32x4 acc[8] = {};
  float m = -1e30f, lsum = 0.f;

  int ks0 = q0 - (WIN - 1); if (ks0 < 0) ks0 = 0;
  ks0 &= ~63;
  const int kend = q0;               // tile [q0, q0+63] covers the diagonal

  auto stage = [&](int b, int k0) {
#pragma unroll
    for (int c = 0; c < 4; ++c) {
      int base = w * 4096 + c * 1024;            // bytes in 16KB tile
      int idx = base / 16 + lane;                // 16B chunk index 0..1023
      {
        int row = idx >> 4;                      // K row (64 rows x 256B)
        int col = (idx & 15) ^ (row & 7);
        gload16(Kb + ((size_t)kvh * T_SEQ + k0 + row) * DH + col * 8,
                (char*)kls[b] + base);
      }
      {
        int d = idx >> 3;                        // V^T row (128 rows x 128B)
        int ch = (idx & 7) ^ (d & 7);
        gload16(Vt + ((size_t)kvh * DH + d) * T_SEQ + k0 + ch * 8,
                (char*)vls[b] + base);
      }
    }
  };

  stage(0, ks0);
  int buf = 0;
  for (int k0 = ks0; k0 <= kend; k0 += 64) {
    bool more = (k0 + 64 <= kend);
    if (more) stage(buf ^ 1, k0 + 64);
    if (more) { asm volatile("s_waitcnt vmcnt(8)" ::: "memory"); }
    else      { asm volatile("s_waitcnt vmcnt(0)" ::: "memory"); }
    __builtin_amdgcn_s_barrier();
    __builtin_amdgcn_sched_barrier(0);

    // wave skip: does [k0, k0+63] intersect [wq0-1023, wq0+15]?
    if (k0 <= wq0 + 15 && k0 + 63 >= wq0 - (WIN - 1)) {
      // ---- QK^T (swapped): S^T[k][q], A=K from LDS, B=Q regs ----
      f32x4 st[4];
      __builtin_amdgcn_s_setprio(1);
#pragma unroll
      for (int kh = 0; kh < 4; ++kh) {
        f32x4 s = {};
        int row = kh * 16 + l15;
        const char* kb = (const char*)kls[buf] + row * 256;
#pragma unroll
        for (int ks = 0; ks < 4; ++ks) {
          int chunk = (ks * 4 + l4) ^ (row & 7);
          bf16x8 kf = *(const bf16x8*)(kb + chunk * 16);
          s = __builtin_amdgcn_mfma_f32_16x16x32_bf16(kf, qf[ks], s, 0, 0, 0);
        }
        st[kh] = s;
      }
      __builtin_amdgcn_s_setprio(0);
      // ---- mask + online softmax in log2 domain (lane owns q = wq0+l15) ----
      const int q = wq0 + l15;
      float pv[4][4];
      float mx = -3e38f;
      if (k0 + 64 <= wq0 && k0 >= wq0 - 1008) {   // interior fast path
#pragma unroll
        for (int kh = 0; kh < 4; ++kh)
#pragma unroll
          for (int i = 0; i < 4; ++i) {
            pv[kh][i] = st[kh][i];
            mx = fmaxf(mx, pv[kh][i]);
          }
      } else {
#pragma unroll
        for (int kh = 0; kh < 4; ++kh)
#pragma unroll
          for (int i = 0; i < 4; ++i) {
            int k = k0 + kh * 16 + l4 * 4 + i;
            bool ok = ((k >> 2) <= (q >> 2)) && (q - k < WIN);
            float s = ok ? st[kh][i] : -3e38f;
            pv[kh][i] = s;
            mx = fmaxf(mx, s);
          }
      }
      mx = fmaxf(mx, __shfl_xor(mx, 16));
      mx = fmaxf(mx, __shfl_xor(mx, 32));
      if (!__all(mx <= m + 11.5f)) {    // defer-max (11.5 ~= 8 * log2e)
        float mn = fmaxf(m, mx);
        float sc = __builtin_amdgcn_exp2f(m - mn);
        m = mn;
        lsum *= sc;
#pragma unroll
        for (int nt = 0; nt < 8; ++nt)
#pragma unroll
          for (int i = 0; i < 4; ++i) acc[nt][i] *= sc;
      }
      float rs = 0.f;
#pragma unroll
      for (int kh = 0; kh < 4; ++kh)
#pragma unroll
        for (int i = 0; i < 4; ++i) {
          float p = __builtin_amdgcn_exp2f(pv[kh][i] - m);
          pv[kh][i] = p;
          rs += p;
        }
      rs += __shfl_xor(rs, 16);
      rs += __shfl_xor(rs, 32);
      lsum += rs;
      // ---- pack P -> per-wave LDS via v_cvt_pk_bf16_f32 ----
      u16* pw = plds[w];
#pragma unroll
      for (int kh = 0; kh < 4; ++kh) {
        unsigned int d0, d1;
        asm("v_cvt_pk_bf16_f32 %0, %1, %2" : "=v"(d0) : "v"(pv[kh][0]), "v"(pv[kh][1]));
        asm("v_cvt_pk_bf16_f32 %0, %1, %2" : "=v"(d1) : "v"(pv[kh][2]), "v"(pv[kh][3]));
        *(unsigned int*)(pw + l15 * 72 + kh * 16 + l4 * 4) = d0;
        *(unsigned int*)(pw + l15 * 72 + kh * 16 + l4 * 4 + 2) = d1;
      }
      bf16x8 pf0 = *(const bf16x8*)(pw + l15 * 72 + l4 * 8);
      bf16x8 pf1 = *(const bf16x8*)(pw + l15 * 72 + 32 + l4 * 8);
      // ---- PV: O^T += V^T * P^T (A = V^T from LDS, B = P), 2 K=32 halves ----
      __builtin_amdgcn_s_setprio(1);
#pragma unroll
      for (int nt = 0; nt < 8; ++nt) {
        int d = nt * 16 + l15;
        int ch0 = l4 ^ (d & 7);
        int ch1 = (4 + l4) ^ (d & 7);
        bf16x8 vf0 = *(const bf16x8*)((const char*)vls[buf] + d * 128 + ch0 * 16);
        bf16x8 vf1 = *(const bf16x8*)((const char*)vls[buf] + d * 128 + ch1 * 16);
        acc[nt] = __builtin_amdgcn_mfma_f32_16x16x32_bf16(vf0, pf0, acc[nt], 0, 0, 0);
        acc[nt] = __builtin_amdgcn_mfma_f32_16x16x32_bf16(vf1, pf1, acc[nt], 0, 0, 0);
      }
      __builtin_amdgcn_s_setprio(0);
    }
    __builtin_amdgcn_sched_barrier(0);
    __builtin_amdgcn_s_barrier();
    buf ^= 1;
  }

  // ---- epilogue ----
  float inv = 1.0f / lsum;
#pragma unroll
  for (int nt = 0; nt < 8; ++nt) {
    u16x4 o;
#pragma unroll
    for (int i = 0; i < 4; ++i) o[i] = f2bf(acc[nt][i] * inv);
    *(u16x4*)(O + (size_t)(wq0 + l15) * (NQ * DH) + h * DH + nt * 16 + l4 * 4) = o;
  }
}

extern "C" void kernel_launch(void* const* d_in, const int* in_sizes, int n_in,
                              void* d_out, int out_size, void* d_ws, size_t ws_size,
                              hipStream_t stream) {
  const float* hidden = (const float*)d_in[0];
  const float* cosb   = (const float*)d_in[1];
  const float* sinb   = (const float*)d_in[2];
  const float* w_qkv  = (const float*)d_in[3];
  const float* qnw    = (const float*)d_in[4];
  const float* knw    = (const float*)d_in[5];
  const float* w_o    = (const float*)d_in[6];
  float* out = (float*)d_out;
  char* ws = (char*)d_ws;

  u16*   wqkvT  = (u16*)(ws);                        // [0, 48M)
  u16*   hid_bf = (u16*)(ws + ((size_t)48 << 20));   // [48M, 64M)
  u16*   qkv_bf = (u16*)(ws + ((size_t)64 << 20));   // [64M, 88M) bf16 qkv (24MB)
  u16*   vn_bf  = (u16*)(ws + ((size_t)88 << 20));   // [88M, 92M) V natural (4MB)
  u16*   q_bf   = (u16*)(ws + ((size_t)112 << 20));  // 16MB
  u16*   k_bf   = (u16*)(ws + ((size_t)128 << 20));  // 4MB
  u16*   vt_bf  = (u16*)(ws + ((size_t)132 << 20));  // 4MB
  u16*   attn_bf= (u16*)(ws + ((size_t)48 << 20));   // reuse hid_bf region
  u16*   woT    = (u16*)(ws);                        // reuse wqkvT region

  f32_to_bf16<<<4096, 256, 0, stream>>>(hidden, hid_bf, T_SEQ * HID);
  transpose_f32_to_bf16<<<dim3(96, 64), dim3(16, 16), 0, stream>>>(w_qkv, wqkvT, HID, 6144);
  // gemm1: 2048x6144x4096, BN=192 -> grid 8x32 = 256 (full fill), bf16 out, 1-barrier/tile
  gemm_1w<3, true><<<256, 512, 0, stream>>>(hid_bf, wqkvT, qkv_bf, 6144, HID, 64);
  transpose_f32_to_bf16<<<dim3(64, 64), dim3(16, 16), 0, stream>>>(w_o, woT, NQ * DH, HID);
  rope_kernel<<<(T_SEQ * 48) / 4, 256, 0, stream>>>(qkv_bf, cosb, sinb, qnw, knw, q_bf, k_bf, vn_bf);
  v_transpose<<<dim3(32, 16), 256, 0, stream>>>(vn_bf, vt_bf);
  attn_kernel<<<dim3(NQ, T_SEQ / 64), 256, 0, stream>>>(q_bf, k_bf, vt_bf, attn_bf);
  // gemm2: 2048x4096x4096, 128^2 tiles -> grid 16x32 = 512 = 2 blocks/CU, f32 out
  gemm_1wh<<<512, 256, 0, stream>>>(attn_bf, woT, out, HID, NQ * DH, 64);
}

// Round 18
// 303.449 us; speedup vs baseline: 1.0897x; 1.0011x over previous
//
#include <hip/hip_runtime.h>
#include <hip/hip_bf16.h>

typedef unsigned short u16;
typedef __attribute__((ext_vector_type(8))) short bf16x8;
typedef __attribute__((ext_vector_type(4))) float f32x4;
typedef __attribute__((ext_vector_type(8))) u16 u16x8;
typedef __attribute__((ext_vector_type(4))) u16 u16x4;

#define T_SEQ 2048
#define HID 4096
#define NQ 32
#define NKV 8
#define DH 128
#define WIN 1024

__device__ __forceinline__ u16 f2bf(float f) {
  union { float f; unsigned int u; } v; v.f = f;
  unsigned int u = v.u;
  unsigned int r = (u + 0x7FFFu + ((u >> 16) & 1u)) >> 16;
  return (u16)r;
}
__device__ __forceinline__ float bf2f(u16 b) {
  union { unsigned int u; float f; } v; v.u = ((unsigned int)b) << 16;
  return v.f;
}

__device__ __forceinline__ void gload16(const void* g, void* l) {
  __builtin_amdgcn_global_load_lds(
      (const __attribute__((address_space(1))) unsigned int*)g,
      (__attribute__((address_space(3))) unsigned int*)l, 16, 0, 0);
}

// ---------------- elementwise f32 -> bf16 ----------------
__global__ __launch_bounds__(256) void f32_to_bf16(const float* __restrict__ in,
                                                   u16* __restrict__ out, int n) {
  int i = (blockIdx.x * 256 + threadIdx.x) * 8;
  if (i >= n) return;
  float4 a = *(const float4*)(in + i);
  float4 b = *(const float4*)(in + i + 4);
  u16x8 r;
  r[0] = f2bf(a.x); r[1] = f2bf(a.y); r[2] = f2bf(a.z); r[3] = f2bf(a.w);
  r[4] = f2bf(b.x); r[5] = f2bf(b.y); r[6] = f2bf(b.z); r[7] = f2bf(b.w);
  *(u16x8*)(out + i) = r;
}

// ---------------- tiled transpose f32 (R x C) -> bf16 (C x R), 64x64 float4 ----------------
__global__ __launch_bounds__(256) void transpose_f32_to_bf16(const float* __restrict__ in,
                                                             u16* __restrict__ out,
                                                             int R, int C) {
  __shared__ float tile[64][65];
  int c0 = blockIdx.x * 64, r0 = blockIdx.y * 64;
  int tx = threadIdx.x, ty = threadIdx.y;    // 16 x 16
#pragma unroll
  for (int i = 0; i < 64; i += 16) {
    float4 v = *(const float4*)(in + (size_t)(r0 + ty + i) * C + c0 + tx * 4);
    tile[ty + i][tx * 4 + 0] = v.x;
    tile[ty + i][tx * 4 + 1] = v.y;
    tile[ty + i][tx * 4 + 2] = v.z;
    tile[ty + i][tx * 4 + 3] = v.w;
  }
  __syncthreads();
#pragma unroll
  for (int i = 0; i < 64; i += 16) {
    u16x4 o;
#pragma unroll
    for (int j = 0; j < 4; ++j) o[j] = f2bf(tile[tx * 4 + j][ty + i]);
    *(u16x4*)(out + (size_t)(c0 + ty + i) * R + r0 + tx * 4) = o;
  }
}

// ---------------- bf16 transpose for V: Vn[2048][1024] -> Vt[1024][2048] ----------------
__global__ __launch_bounds__(256) void v_transpose(const u16* __restrict__ Vn,
                                                   u16* __restrict__ Vt) {
  __shared__ u16 tile[64][68];
  int tx = threadIdx.x & 15, ty = threadIdx.x >> 4;   // 16 x 16
  int t0 = blockIdx.x * 64, dh0 = blockIdx.y * 64;
#pragma unroll
  for (int i = 0; i < 64; i += 16) {
    u16x4 v = *(const u16x4*)(Vn + (size_t)(t0 + ty + i) * 1024 + dh0 + tx * 4);
    tile[ty + i][tx * 4 + 0] = v[0];
    tile[ty + i][tx * 4 + 1] = v[1];
    tile[ty + i][tx * 4 + 2] = v[2];
    tile[ty + i][tx * 4 + 3] = v[3];
  }
  __syncthreads();
#pragma unroll
  for (int i = 0; i < 64; i += 16) {
    u16x4 o;
#pragma unroll
    for (int j = 0; j < 4; ++j) o[j] = tile[tx * 4 + j][ty + i];
    *(u16x4*)(Vt + (size_t)(dh0 + ty + i) * 2048 + t0 + tx * 4) = o;
  }
}

// ---------------- gemm_1w: 256xBN GEMM, ONE barrier per K-tile, free scheduling --------
// Window(t): rd afA[4](slot t&1) + bfr[2NF](slot t%3) | stage A(t+1)->(t+1)&1 |
//   stage B(t+2)->(t+2)%3 | setprio | 8NF MFMA | lgkm0 | vmcnt(NB) | barrier.
// R17 change: NO lgkmcnt(0)/sched_barrier BEFORE the MFMAs -- reads are
// compiler-visible C++ loads, so hipcc emits counted lgkmcnt per-use and the
// LDS drain overlaps the MFMA cluster (m97 mechanism; the old pre-MFMA fence
// was the hand-built serial wall, m141 failure mode). Cross-wave slot hazard
// (slot s re-staged in window s+1) only needs lgkm0 before the END barrier.
// vmcnt ledger unchanged: vmcnt(NB) retires A(t+1)+B(t+1), keeps B(t+2).
template <int NF, bool BF16OUT>
__global__ __launch_bounds__(512, 2) void gemm_1w(const u16* __restrict__ A,
                                                  const u16* __restrict__ Bt,
                                                  void* __restrict__ Cv,
                                                  int N, int K, int NT) {
  constexpr int HN = NF * 16;
  constexpr int BN = 4 * HN;
  constexpr int NB = BN / 64;
  __shared__ u16 lsA[2][16384];     // 2 x 32KB
  __shared__ u16 lsB[3][BN * 64];   // 3 x (BN*128B)
  const int tid = threadIdx.x;
  const int lane = tid & 63, w = tid >> 6;
  const int wm = w >> 1, wn = w & 1;           // 4M x 2N
  const int l15 = lane & 15, l4 = lane >> 4;

  const int nwg = gridDim.x;
  const int cpx = nwg >> 3;
  const int bid = blockIdx.x;
  const int swz = (bid & 7) * cpx + (bid >> 3);
  const int bm = (swz & 7) * 256;
  const int bn = (swz >> 3) * BN;

  auto stageA = [&](int unit, int slot, int kt) {
    int r = tid >> 3, cp = tid & 7;
    int scp = cp ^ (r & 7);
    gload16(A + (size_t)(bm + unit * 64 + r) * K + kt * 64 + scp * 8,
            (char*)lsA[slot] + (unit * 512 + tid) * 16);
  };
  auto stageB = [&](int unit, int slot, int kt) {
    int r = tid >> 3, cp = tid & 7;
    int scp = cp ^ (r & 7);
    gload16(Bt + (size_t)(bn + unit * 64 + r) * K + kt * 64 + scp * 8,
            (char*)lsB[slot] + (unit * 512 + tid) * 16);
  };
  auto rdA = [&](int slot, int mf, int ks) -> bf16x8 {
    int r = wm * 64 + mf * 16 + l15;
    int ch = (ks * 4 + l4) ^ (r & 7);
    return *(const bf16x8*)(lsA[slot] + r * 64 + ch * 8);
  };
  auto rdB = [&](int slot, int nf, int ks) -> bf16x8 {
    int r = wn * 2 * HN + nf * 16 + l15;
    int ch = (ks * 4 + l4) ^ (r & 7);
    return *(const bf16x8*)(lsB[slot] + r * 64 + ch * 8);
  };

#define WAIT_NB() do { if constexpr (NB == 3) asm volatile("s_waitcnt vmcnt(3)" ::: "memory"); \
                       else                   asm volatile("s_waitcnt vmcnt(2)" ::: "memory"); } while (0)

  f32x4 acc[4][2 * NF] = {};
  bf16x8 afA[4][2], bfr[2 * NF][2];

  stageA(0, 0, 0); stageA(1, 0, 0); stageA(2, 0, 0); stageA(3, 0, 0);
#pragma unroll
  for (int u = 0; u < NB; ++u) stageB(u, 0, 0);
#pragma unroll
  for (int u = 0; u < NB; ++u) stageB(u, 1, 1);
  WAIT_NB();
  __builtin_amdgcn_s_barrier();

  for (int t = 0; t < NT; ++t) {
    const int sA = t & 1, sB = t % 3;
    const int ktA = (t + 1 < NT) ? t + 1 : NT - 1;
    const int ktB = (t + 2 < NT) ? t + 2 : NT - 1;

#pragma unroll
    for (int mf = 0; mf < 4; ++mf)
#pragma unroll
      for (int ks = 0; ks < 2; ++ks) afA[mf][ks] = rdA(sA, mf, ks);
#pragma unroll
    for (int nf = 0; nf < 2 * NF; ++nf)
#pragma unroll
      for (int ks = 0; ks < 2; ++ks) bfr[nf][ks] = rdB(sB, nf, ks);
    stageA(0, (t + 1) & 1, ktA); stageA(1, (t + 1) & 1, ktA);
    stageA(2, (t + 1) & 1, ktA); stageA(3, (t + 1) & 1, ktA);
#pragma unroll
    for (int u = 0; u < NB; ++u) stageB(u, (t + 2) % 3, ktB);
    __builtin_amdgcn_s_setprio(1);
#pragma unroll
    for (int mf = 0; mf < 4; ++mf)
#pragma unroll
      for (int nf = 0; nf < 2 * NF; ++nf) {
        acc[mf][nf] = __builtin_amdgcn_mfma_f32_16x16x32_bf16(afA[mf][0], bfr[nf][0], acc[mf][nf], 0, 0, 0);
        acc[mf][nf] = __builtin_amdgcn_mfma_f32_16x16x32_bf16(afA[mf][1], bfr[nf][1], acc[mf][nf], 0, 0, 0);
      }
    __builtin_amdgcn_s_setprio(0);
    asm volatile("s_waitcnt lgkmcnt(0)" ::: "memory");
    WAIT_NB();
    __builtin_amdgcn_s_barrier();
  }

  asm volatile("s_waitcnt vmcnt(0)" ::: "memory");

#pragma unroll
  for (int mi = 0; mi < 4; ++mi)
#pragma unroll
    for (int ni = 0; ni < 2 * NF; ++ni) {
      int row = bm + wm * 64 + mi * 16 + l4 * 4;
      int col = bn + wn * 2 * HN + ni * 16 + l15;
      if constexpr (BF16OUT) {
        u16* dst = (u16*)Cv;
#pragma unroll
        for (int j = 0; j < 4; ++j)
          dst[(size_t)(row + j) * N + col] = f2bf(acc[mi][ni][j]);
      } else {
        float* p = (float*)Cv + (size_t)row * N + col;
        p[0] = acc[mi][ni][0];
        p[(size_t)N] = acc[mi][ni][1];
        p[2 * (size_t)N] = acc[mi][ni][2];
        p[3 * (size_t)N] = acc[mi][ni][3];
      }
    }
#undef WAIT_NB
}

// ---------------- gemm_1wh: 128x128 1-window GEMM, 4 waves, 2 blocks/CU (gemm2) --------
// Same R17 change: MFMAs gate on compiler-inserted counted lgkmcnt; explicit
// lgkm0 moved to after the cluster (cross-wave slot safety before barrier).
__global__ __launch_bounds__(256, 2) void gemm_1wh(const u16* __restrict__ A,
                                                   const u16* __restrict__ Bt,
                                                   float* __restrict__ C,
                                                   int N, int K, int NT) {
  __shared__ u16 lsA[2][8192];    // 2 x 16KB (128 rows x 64 k)
  __shared__ u16 lsB[3][8192];    // 3 x 16KB
  const int tid = threadIdx.x;
  const int lane = tid & 63, w = tid >> 6;     // 4 waves
  const int wm = w >> 1, wn = w & 1;           // 2M x 2N
  const int l15 = lane & 15, l4 = lane >> 4;

  const int nwg = gridDim.x;                   // 512, %8==0
  const int cpx = nwg >> 3;
  const int bid = blockIdx.x;
  const int swz = (bid & 7) * cpx + (bid >> 3);
  const int bm = (swz & 15) * 128;             // 16 M-tiles (x-major)
  const int bn = (swz >> 4) * 128;             // 32 N-tiles

  auto stageA = [&](int unit, int slot, int kt) {
    int r = unit * 32 + (tid >> 3), cp = tid & 7;
    int scp = cp ^ (r & 7);
    gload16(A + (size_t)(bm + r) * K + kt * 64 + scp * 8,
            (char*)lsA[slot] + (unit * 256 + tid) * 16);
  };
  auto stageB = [&](int unit, int slot, int kt) {
    int r = unit * 32 + (tid >> 3), cp = tid & 7;
    int scp = cp ^ (r & 7);
    gload16(Bt + (size_t)(bn + r) * K + kt * 64 + scp * 8,
            (char*)lsB[slot] + (unit * 256 + tid) * 16);
  };
  auto rdA = [&](int slot, int mf, int ks) -> bf16x8 {
    int r = wm * 64 + mf * 16 + l15;
    int ch = (ks * 4 + l4) ^ (r & 7);
    return *(const bf16x8*)(lsA[slot] + r * 64 + ch * 8);
  };
  auto rdB = [&](int slot, int nf, int ks) -> bf16x8 {
    int r = wn * 64 + nf * 16 + l15;
    int ch = (ks * 4 + l4) ^ (r & 7);
    return *(const bf16x8*)(lsB[slot] + r * 64 + ch * 8);
  };

  f32x4 acc[4][4] = {};
  bf16x8 afA[4][2], bfr[4][2];

#pragma unroll
  for (int u = 0; u < 4; ++u) stageA(u, 0, 0);
#pragma unroll
  for (int u = 0; u < 4; ++u) stageB(u, 0, 0);
#pragma unroll
  for (int u = 0; u < 4; ++u) stageB(u, 1, 1);
  asm volatile("s_waitcnt vmcnt(4)" ::: "memory");
  __builtin_amdgcn_s_barrier();

  for (int t = 0; t < NT; ++t) {
    const int sA = t & 1, sB = t % 3;
    const int ktA = (t + 1 < NT) ? t + 1 : NT - 1;
    const int ktB = (t + 2 < NT) ? t + 2 : NT - 1;

#pragma unroll
    for (int mf = 0; mf < 4; ++mf)
#pragma unroll
      for (int ks = 0; ks < 2; ++ks) afA[mf][ks] = rdA(sA, mf, ks);
#pragma unroll
    for (int nf = 0; nf < 4; ++nf)
#pragma unroll
      for (int ks = 0; ks < 2; ++ks) bfr[nf][ks] = rdB(sB, nf, ks);
#pragma unroll
    for (int u = 0; u < 4; ++u) stageA(u, (t + 1) & 1, ktA);
#pragma unroll
    for (int u = 0; u < 4; ++u) stageB(u, (t + 2) % 3, ktB);
    __builtin_amdgcn_s_setprio(1);
#pragma unroll
    for (int mf = 0; mf < 4; ++mf)
#pragma unroll
      for (int nf = 0; nf < 4; ++nf) {
        acc[mf][nf] = __builtin_amdgcn_mfma_f32_16x16x32_bf16(afA[mf][0], bfr[nf][0], acc[mf][nf], 0, 0, 0);
        acc[mf][nf] = __builtin_amdgcn_mfma_f32_16x16x32_bf16(afA[mf][1], bfr[nf][1], acc[mf][nf], 0, 0, 0);
      }
    __builtin_amdgcn_s_setprio(0);
    asm volatile("s_waitcnt lgkmcnt(0)" ::: "memory");
    asm volatile("s_waitcnt vmcnt(4)" ::: "memory");   // tile t+1 resident
    __builtin_amdgcn_s_barrier();
  }

  asm volatile("s_waitcnt vmcnt(0)" ::: "memory");

#pragma unroll
  for (int mi = 0; mi < 4; ++mi)
#pragma unroll
    for (int ni = 0; ni < 4; ++ni) {
      int row = bm + wm * 64 + mi * 16 + l4 * 4;
      int col = bn + wn * 64 + ni * 16 + l15;
      float* p = C + (size_t)row * N + col;
      p[0] = acc[mi][ni][0];
      p[(size_t)N] = acc[mi][ni][1];
      p[2 * (size_t)N] = acc[mi][ni][2];
      p[3 * (size_t)N] = acc[mi][ni][3];
    }
}

// ---------------- RMSNorm + RoPE + layout (bf16 qkv in; Q scaled incl log2e; V natural) ----
__global__ __launch_bounds__(256) void rope_kernel(const u16* __restrict__ qkv,
                                                   const float* __restrict__ cosb,
                                                   const float* __restrict__ sinb,
                                                   const float* __restrict__ qw,
                                                   const float* __restrict__ kw,
                                                   u16* __restrict__ Qo,
                                                   u16* __restrict__ Ko,
                                                   u16* __restrict__ Vn) {
  int wid = threadIdx.x >> 6, lane = threadIdx.x & 63;
  int item = blockIdx.x * 4 + wid;          // item = t*48 + hid
  int t = item / 48, hid = item % 48;
  const u16* x = qkv + (size_t)t * 6144 + hid * 128;
  float x1 = bf2f(x[lane]), x2 = bf2f(x[lane + 64]);
  if (hid < NQ + NKV) {
    float ss = x1 * x1 + x2 * x2;
    for (int off = 32; off; off >>= 1) ss += __shfl_xor(ss, off);
    float inv = rsqrtf(ss * (1.0f / 128.0f) + 1e-6f);
    const float* wn = (hid < NQ) ? qw : kw;
    float n1 = x1 * inv * wn[lane], n2 = x2 * inv * wn[lane + 64];
    float c1 = cosb[t * 128 + lane], s1 = sinb[t * 128 + lane];
    float c2 = cosb[t * 128 + lane + 64], s2 = sinb[t * 128 + lane + 64];
    float o1 = n1 * c1 - n2 * s1;
    float o2 = n2 * c2 + n1 * s2;
    if (hid < NQ) {
      // fold 1/sqrt(128) AND log2(e) into Q: softmax runs in log2 domain
      const float scale = 0.08838834764831845f * 1.44269504088896341f;
      u16* q = Qo + ((size_t)hid * T_SEQ + t) * 128;
      q[lane] = f2bf(o1 * scale); q[lane + 64] = f2bf(o2 * scale);
    } else {
      int h = hid - NQ;
      u16* k = Ko + ((size_t)h * T_SEQ + t) * 128;
      k[lane] = f2bf(o1); k[lane + 64] = f2bf(o2);
    }
  } else {
    int h = hid - (NQ + NKV);
    u16* vn = Vn + (size_t)t * 1024 + h * 128;   // coalesced natural layout
    vn[lane] = x[lane];
    vn[lane + 64] = x[lane + 64];
  }
}

// ---------------- flash attention: 4 waves/block, QBLK=64, KVBLK=64 (R16 form, frozen) ----
__global__ __launch_bounds__(256) void attn_kernel(const u16* __restrict__ Q,
                                                   const u16* __restrict__ Kb,
                                                   const u16* __restrict__ Vt,
                                                   u16* __restrict__ O) {
  __shared__ u16 kls[2][64 * 128];   // 16KB per buf
  __shared__ u16 vls[2][128 * 64];   // 16KB per buf
  __shared__ u16 plds[4][16 * 72];   // per-wave P [16 q][64 k] pad to 72

  const int tid = threadIdx.x;
  const int lane = tid & 63, w = tid >> 6;
  const int l15 = lane & 15, l4 = lane >> 4;
  const int h = blockIdx.x;          // q head
  const int q0 = blockIdx.y * 64;    // block q base
  const int wq0 = q0 + w * 16;       // wave q base
  const int kvh = h >> 2;

  bf16x8 qf[4];
  {
    const u16* qrow = Q + ((size_t)h * T_SEQ + (wq0 + l15)) * DH;
    for (int ks = 0; ks < 4; ++ks)
      qf[ks] = *(const bf16x8*)(qrow + ks * 32 + l4 * 8);
  }

  f32x4 acc[8] = {};
  float m = -1e30f, lsum = 0.f;

  int ks0 = q0 - (WIN - 1); if (ks0 < 0) ks0 = 0;
  ks0 &= ~63;
  const int kend = q0;               // tile [q0, q0+63] covers the diagonal

  auto stage = [&](int b, int k0) {
#pragma unroll
    for (int c = 0; c < 4; ++c) {
      int base = w * 4096 + c * 1024;            // bytes in 16KB tile
      int idx = base / 16 + lane;                // 16B chunk index 0..1023
      {
        int row = idx >> 4;                      // K row (64 rows x 256B)
        int col = (idx & 15) ^ (row & 7);
        gload16(Kb + ((size_t)kvh * T_SEQ + k0 + row) * DH + col * 8,
                (char*)kls[b] + base);
      }
      {
        int d = idx >> 3;                        // V^T row (128 rows x 128B)
        int ch = (idx & 7) ^ (d & 7);
        gload16(Vt + ((size_t)kvh * DH + d) * T_SEQ + k0 + ch * 8,
                (char*)vls[b] + base);
      }
    }
  };

  stage(0, ks0);
  int buf = 0;
  for (int k0 = ks0; k0 <= kend; k0 += 64) {
    bool more = (k0 + 64 <= kend);
    if (more) stage(buf ^ 1, k0 + 64);
    if (more) { asm volatile("s_waitcnt vmcnt(8)" ::: "memory"); }
    else      { asm volatile("s_waitcnt vmcnt(0)" ::: "memory"); }
    __builtin_amdgcn_s_barrier();
    __builtin_amdgcn_sched_barrier(0);

    // wave skip: does [k0, k0+63] intersect [wq0-1023, wq0+15]?
    if (k0 <= wq0 + 15 && k0 + 63 >= wq0 - (WIN - 1)) {
      // ---- QK^T (swapped): S^T[k][q], A=K from LDS, B=Q regs ----
      f32x4 st[4];
      __builtin_amdgcn_s_setprio(1);
#pragma unroll
      for (int kh = 0; kh < 4; ++kh) {
        f32x4 s = {};
        int row = kh * 16 + l15;
        const char* kb = (const char*)kls[buf] + row * 256;
#pragma unroll
        for (int ks = 0; ks < 4; ++ks) {
          int chunk = (ks * 4 + l4) ^ (row & 7);
          bf16x8 kf = *(const bf16x8*)(kb + chunk * 16);
          s = __builtin_amdgcn_mfma_f32_16x16x32_bf16(kf, qf[ks], s, 0, 0, 0);
        }
        st[kh] = s;
      }
      __builtin_amdgcn_s_setprio(0);
      // ---- mask + online softmax in log2 domain (lane owns q = wq0+l15) ----
      const int q = wq0 + l15;
      float pv[4][4];
      float mx = -3e38f;
      if (k0 + 64 <= wq0 && k0 >= wq0 - 1008) {   // interior fast path
#pragma unroll
        for (int kh = 0; kh < 4; ++kh)
#pragma unroll
          for (int i = 0; i < 4; ++i) {
            pv[kh][i] = st[kh][i];
            mx = fmaxf(mx, pv[kh][i]);
          }
      } else {
#pragma unroll
        for (int kh = 0; kh < 4; ++kh)
#pragma unroll
          for (int i = 0; i < 4; ++i) {
            int k = k0 + kh * 16 + l4 * 4 + i;
            bool ok = ((k >> 2) <= (q >> 2)) && (q - k < WIN);
            float s = ok ? st[kh][i] : -3e38f;
            pv[kh][i] = s;
            mx = fmaxf(mx, s);
          }
      }
      mx = fmaxf(mx, __shfl_xor(mx, 16));
      mx = fmaxf(mx, __shfl_xor(mx, 32));
      if (!__all(mx <= m + 11.5f)) {    // defer-max (11.5 ~= 8 * log2e)
        float mn = fmaxf(m, mx);
        float sc = __builtin_amdgcn_exp2f(m - mn);
        m = mn;
        lsum *= sc;
#pragma unroll
        for (int nt = 0; nt < 8; ++nt)
#pragma unroll
          for (int i = 0; i < 4; ++i) acc[nt][i] *= sc;
      }
      float rs = 0.f;
#pragma unroll
      for (int kh = 0; kh < 4; ++kh)
#pragma unroll
        for (int i = 0; i < 4; ++i) {
          float p = __builtin_amdgcn_exp2f(pv[kh][i] - m);
          pv[kh][i] = p;
          rs += p;
        }
      rs += __shfl_xor(rs, 16);
      rs += __shfl_xor(rs, 32);
      lsum += rs;
      // ---- pack P -> per-wave LDS via v_cvt_pk_bf16_f32 ----
      u16* pw = plds[w];
#pragma unroll
      for (int kh = 0; kh < 4; ++kh) {
        unsigned int d0, d1;
        asm("v_cvt_pk_bf16_f32 %0, %1, %2" : "=v"(d0) : "v"(pv[kh][0]), "v"(pv[kh][1]));
        asm("v_cvt_pk_bf16_f32 %0, %1, %2" : "=v"(d1) : "v"(pv[kh][2]), "v"(pv[kh][3]));
        *(unsigned int*)(pw + l15 * 72 + kh * 16 + l4 * 4) = d0;
        *(unsigned int*)(pw + l15 * 72 + kh * 16 + l4 * 4 + 2) = d1;
      }
      bf16x8 pf0 = *(const bf16x8*)(pw + l15 * 72 + l4 * 8);
      bf16x8 pf1 = *(const bf16x8*)(pw + l15 * 72 + 32 + l4 * 8);
      // ---- PV: O^T += V^T * P^T (A = V^T from LDS, B = P), 2 K=32 halves ----
      __builtin_amdgcn_s_setprio(1);
#pragma unroll
      for (int nt = 0; nt < 8; ++nt) {
        int d = nt * 16 + l15;
        int ch0 = l4 ^ (d & 7);
        int ch1 = (4 + l4) ^ (d & 7);
        bf16x8 vf0 = *(const bf16x8*)((const char*)vls[buf] + d * 128 + ch0 * 16);
        bf16x8 vf1 = *(const bf16x8*)((const char*)vls[buf] + d * 128 + ch1 * 16);
        acc[nt] = __builtin_amdgcn_mfma_f32_16x16x32_bf16(vf0, pf0, acc[nt], 0, 0, 0);
        acc[nt] = __builtin_amdgcn_mfma_f32_16x16x32_bf16(vf1, pf1, acc[nt], 0, 0, 0);
      }
      __builtin_amdgcn_s_setprio(0);
    }
    __builtin_amdgcn_sched_barrier(0);
    __builtin_amdgcn_s_barrier();
    buf ^= 1;
  }

  // ---- epilogue ----
  float inv = 1.0f / lsum;
#pragma unroll
  for (int nt = 0; nt < 8; ++nt) {
    u16x4 o;
#pragma unroll
    for (int i = 0; i < 4; ++i) o[i] = f2bf(acc[nt][i] * inv);
    *(u16x4*)(O + (size_t)(wq0 + l15) * (NQ * DH) + h * DH + nt * 16 + l4 * 4) = o;
  }
}

extern "C" void kernel_launch(void* const* d_in, const int* in_sizes, int n_in,
                              void* d_out, int out_size, void* d_ws, size_t ws_size,
                              hipStream_t stream) {
  const float* hidden = (const float*)d_in[0];
  const float* cosb   = (const float*)d_in[1];
  const float* sinb   = (const float*)d_in[2];
  const float* w_qkv  = (const float*)d_in[3];
  const float* qnw    = (const float*)d_in[4];
  const float* knw    = (const float*)d_in[5];
  const float* w_o    = (const float*)d_in[6];
  float* out = (float*)d_out;
  char* ws = (char*)d_ws;

  u16*   wqkvT  = (u16*)(ws);                        // [0, 48M)
  u16*   hid_bf = (u16*)(ws + ((size_t)48 << 20));   // [48M, 64M)
  u16*   qkv_bf = (u16*)(ws + ((size_t)64 << 20));   // [64M, 88M) bf16 qkv (24MB)
  u16*   vn_bf  = (u16*)(ws + ((size_t)88 << 20));   // [88M, 92M) V natural (4MB)
  u16*   q_bf   = (u16*)(ws + ((size_t)112 << 20));  // 16MB
  u16*   k_bf   = (u16*)(ws + ((size_t)128 << 20));  // 4MB
  u16*   vt_bf  = (u16*)(ws + ((size_t)132 << 20));  // 4MB
  u16*   attn_bf= (u16*)(ws + ((size_t)48 << 20));   // reuse hid_bf region
  u16*   woT    = (u16*)(ws);                        // reuse wqkvT region

  f32_to_bf16<<<4096, 256, 0, stream>>>(hidden, hid_bf, T_SEQ * HID);
  transpose_f32_to_bf16<<<dim3(96, 64), dim3(16, 16), 0, stream>>>(w_qkv, wqkvT, HID, 6144);
  // gemm1: 2048x6144x4096, BN=192 -> grid 8x32 = 256 (full fill), bf16 out, 1-barrier/tile
  gemm_1w<3, true><<<256, 512, 0, stream>>>(hid_bf, wqkvT, qkv_bf, 6144, HID, 64);
  transpose_f32_to_bf16<<<dim3(64, 64), dim3(16, 16), 0, stream>>>(w_o, woT, NQ * DH, HID);
  rope_kernel<<<(T_SEQ * 48) / 4, 256, 0, stream>>>(qkv_bf, cosb, sinb, qnw, knw, q_bf, k_bf, vn_bf);
  v_transpose<<<dim3(32, 16), 256, 0, stream>>>(vn_bf, vt_bf);
  attn_kernel<<<dim3(NQ, T_SEQ / 64), 256, 0, stream>>>(q_bf, k_bf, vt_bf, attn_bf);
  // gemm2: 2048x4096x4096, 128^2 tiles -> grid 16x32 = 512 = 2 blocks/CU, f32 out
  gemm_1wh<<<512, 256, 0, stream>>>(attn_bf, woT, out, HID, NQ * DH, 64);
}